// Round 2
// baseline (10320.672 us; speedup 1.0000x reference)
//
#include <hip/hip_runtime.h>

#define BB 64      // batch
#define DD 512     // d_model = d_state = d_att
#define TT 32      // steps

__device__ __forceinline__ float dot4(const float4 a, const float4 b) {
  return a.x * b.x + a.y * b.y + a.z * b.z + a.w * b.w;
}

// ---------------------------------------------------------------- zero
__global__ void zero_k(float* __restrict__ out, int n4) {
  const int i = blockIdx.x * blockDim.x + threadIdx.x;
  if (i < n4) ((float4*)out)[i] = make_float4(0.f, 0.f, 0.f, 0.f);
}

// ---------------------------------------------------------------- small folded vectors (+ barrier reset)
__global__ void vecs_k(const float* __restrict__ wq, const float* __restrict__ bk,
                       const float* __restrict__ wk, const float* __restrict__ bq,
                       float* __restrict__ kqb, float* __restrict__ wkbq,
                       float* __restrict__ bqbk, unsigned* __restrict__ bar) {
  const int tid = threadIdx.x, bz = blockIdx.x;
  if (bz < 2) {
    const int d = bz * 256 + tid;
    float s = 0.f;
    for (int e = 0; e < DD; ++e) s += wq[e * DD + d] * bk[e];
    kqb[d] = s;
  } else {
    const int k = (bz - 2) * 256 + tid;
    float s = 0.f;
    for (int e = 0; e < DD; ++e) s += bq[e] * wk[e * DD + k];
    wkbq[k] = s;
    if (bz == 2 && tid == 0) {
      float t2 = 0.f;
      for (int e = 0; e < DD; ++e) t2 += bq[e] * bk[e];
      *bqbk = t2;
    }
    if (bz == 3 && tid == 0) *bar = 0u;   // reset grid barrier each invocation
  }
}

// ---------------------------------------------------------------- fast fp32 GEMM, 128x64 tile, 8x4 micro
__global__ __launch_bounds__(256) void gemm128_k(
    const float* __restrict__ A, int lda, int a_trans,
    const float* __restrict__ B, int ldb, int boff, int b_trans,
    const float* __restrict__ bias, float* __restrict__ C, long c_stride_z, int ldc,
    int kfrom, int klen, int act) {
  __shared__ __align__(16) float As[16][132];
  __shared__ __align__(16) float Bs[16][68];
  const int tid = threadIdx.x;
  const int tx = tid & 15, ty = tid >> 4;
  const int m0 = blockIdx.x * 128, n0 = blockIdx.y * 64;
  const int kbase = kfrom + blockIdx.z * klen;
  float* Ce = C + (long)blockIdx.z * c_stride_z;
  float acc[8][4];
#pragma unroll
  for (int i = 0; i < 8; ++i)
#pragma unroll
    for (int j = 0; j < 4; ++j) acc[i][j] = 0.f;

  for (int k0 = kbase; k0 < kbase + klen; k0 += 16) {
    if (!a_trans) {
      const int row = tid >> 1, half = tid & 1;
      const float* ap = A + (long)(m0 + row) * lda + k0 + half * 8;
      const float4 a0 = *(const float4*)ap;
      const float4 a1 = *(const float4*)(ap + 4);
      const int kb = half * 8;
      As[kb + 0][row] = a0.x; As[kb + 1][row] = a0.y; As[kb + 2][row] = a0.z; As[kb + 3][row] = a0.w;
      As[kb + 4][row] = a1.x; As[kb + 5][row] = a1.y; As[kb + 6][row] = a1.z; As[kb + 7][row] = a1.w;
    } else {
      const int kk = tid >> 4, mseg = tid & 15;
      const float* ap = A + (long)(k0 + kk) * lda + m0 + mseg * 8;
      *(float4*)&As[kk][mseg * 8] = *(const float4*)ap;
      *(float4*)&As[kk][mseg * 8 + 4] = *(const float4*)(ap + 4);
    }
    if (!b_trans) {
      const int n = tid >> 2, q = tid & 3;
      const float4 b0 = *(const float4*)(B + (long)(n0 + n) * ldb + boff + k0 + q * 4);
      Bs[q * 4 + 0][n] = b0.x; Bs[q * 4 + 1][n] = b0.y; Bs[q * 4 + 2][n] = b0.z; Bs[q * 4 + 3][n] = b0.w;
    } else {
      const int kk = tid >> 4, nq = tid & 15;
      *(float4*)&Bs[kk][nq * 4] = *(const float4*)(B + (long)(k0 + kk) * ldb + boff + n0 + nq * 4);
    }
    __syncthreads();
#pragma unroll
    for (int kk = 0; kk < 16; ++kk) {
      const float4 a0 = *(const float4*)&As[kk][ty * 8];
      const float4 a1 = *(const float4*)&As[kk][ty * 8 + 4];
      const float4 b0 = *(const float4*)&Bs[kk][tx * 4];
      const float am[8] = {a0.x, a0.y, a0.z, a0.w, a1.x, a1.y, a1.z, a1.w};
#pragma unroll
      for (int i = 0; i < 8; ++i) {
        acc[i][0] += am[i] * b0.x; acc[i][1] += am[i] * b0.y;
        acc[i][2] += am[i] * b0.z; acc[i][3] += am[i] * b0.w;
      }
    }
    __syncthreads();
  }
  float4 bv = make_float4(0.f, 0.f, 0.f, 0.f);
  if (bias) bv = *(const float4*)(bias + n0 + tx * 4);
#pragma unroll
  for (int i = 0; i < 8; ++i) {
    const int m = m0 + ty * 8 + i;
    float4 v = make_float4(acc[i][0] + bv.x, acc[i][1] + bv.y, acc[i][2] + bv.z, acc[i][3] + bv.w);
    if (act == 1) { v.x = tanhf(v.x); v.y = tanhf(v.y); v.z = tanhf(v.z); v.w = tanhf(v.w); }
    *(float4*)&Ce[(long)m * ldc + n0 + tx * 4] = v;
  }
}

// ---------------------------------------------------------------- dual big GEMM: z=0 -> C0 = A@B0^T+bias0; z=1 -> C1 = A@B1^T+bias1
// Row-major [*,512], K=512, M=4096, N=512. Grid (32,8,2) = 512 blocks -> 2 blocks/CU.
__global__ __launch_bounds__(256) void gemm128_dual_k(
    const float* __restrict__ A,
    const float* __restrict__ B0, const float* __restrict__ bias0, float* __restrict__ C0,
    const float* __restrict__ B1, const float* __restrict__ bias1, float* __restrict__ C1) {
  __shared__ __align__(16) float As[16][132];
  __shared__ __align__(16) float Bs[16][68];
  const int tid = threadIdx.x;
  const int tx = tid & 15, ty = tid >> 4;
  const int m0 = blockIdx.x * 128, n0 = blockIdx.y * 64;
  const float* B = blockIdx.z ? B1 : B0;
  const float* bias = blockIdx.z ? bias1 : bias0;
  float* C = blockIdx.z ? C1 : C0;
  float acc[8][4];
#pragma unroll
  for (int i = 0; i < 8; ++i)
#pragma unroll
    for (int j = 0; j < 4; ++j) acc[i][j] = 0.f;

  for (int k0 = 0; k0 < 512; k0 += 16) {
    {
      const int row = tid >> 1, half = tid & 1;
      const float* ap = A + (long)(m0 + row) * 512 + k0 + half * 8;
      const float4 a0 = *(const float4*)ap;
      const float4 a1 = *(const float4*)(ap + 4);
      const int kb = half * 8;
      As[kb + 0][row] = a0.x; As[kb + 1][row] = a0.y; As[kb + 2][row] = a0.z; As[kb + 3][row] = a0.w;
      As[kb + 4][row] = a1.x; As[kb + 5][row] = a1.y; As[kb + 6][row] = a1.z; As[kb + 7][row] = a1.w;
    }
    {
      const int n = tid >> 2, q = tid & 3;
      const float4 b0 = *(const float4*)(B + (long)(n0 + n) * 512 + k0 + q * 4);
      Bs[q * 4 + 0][n] = b0.x; Bs[q * 4 + 1][n] = b0.y; Bs[q * 4 + 2][n] = b0.z; Bs[q * 4 + 3][n] = b0.w;
    }
    __syncthreads();
#pragma unroll
    for (int kk = 0; kk < 16; ++kk) {
      const float4 a0 = *(const float4*)&As[kk][ty * 8];
      const float4 a1 = *(const float4*)&As[kk][ty * 8 + 4];
      const float4 b0 = *(const float4*)&Bs[kk][tx * 4];
      const float am[8] = {a0.x, a0.y, a0.z, a0.w, a1.x, a1.y, a1.z, a1.w};
#pragma unroll
      for (int i = 0; i < 8; ++i) {
        acc[i][0] += am[i] * b0.x; acc[i][1] += am[i] * b0.y;
        acc[i][2] += am[i] * b0.z; acc[i][3] += am[i] * b0.w;
      }
    }
    __syncthreads();
  }
  const float4 bvv = *(const float4*)(bias + n0 + tx * 4);
#pragma unroll
  for (int i = 0; i < 8; ++i) {
    const int m = m0 + ty * 8 + i;
    float4 v = make_float4(acc[i][0] + bvv.x, acc[i][1] + bvv.y, acc[i][2] + bvv.z, acc[i][3] + bvv.w);
    *(float4*)&C[(long)m * 512 + n0 + tx * 4] = v;
  }
}

// sum 4 split-K partials (fixed order -> deterministic)
__global__ void combine4_k(const float* __restrict__ p, float* __restrict__ out) {
  const int i = blockIdx.x * blockDim.x + threadIdx.x;  // f4 index, 65536 total
  const float4 a = ((const float4*)p)[i];
  const float4 b = ((const float4*)p)[i + 65536];
  const float4 c = ((const float4*)p)[i + 131072];
  const float4 d = ((const float4*)p)[i + 196608];
  ((float4*)out)[i] = make_float4(a.x + b.x + c.x + d.x, a.y + b.y + c.y + d.y,
                                  a.z + b.z + c.z + d.z, a.w + b.w + c.w + d.w);
}

// ---------------------------------------------------------------- generic fp32 GEMM (kept for small shapes)
__global__ __launch_bounds__(256) void gemm_k(
    const float* __restrict__ A, int lda, int a_trans,
    const float* __restrict__ B, int ldb, int boff, int b_trans,
    const float* __restrict__ bias,
    float* __restrict__ C, int ldc, int M, int N, int K, int act) {
  __shared__ __align__(16) float As2[32][68];
  __shared__ __align__(16) float Bs2[32][68];
  const int tid = threadIdx.x;
  const int tx = tid & 15, ty = tid >> 4;
  const int m0 = blockIdx.x * 64, n0 = blockIdx.y * 64;
  float acc[4][4] = {};
  for (int k0 = 0; k0 < K; k0 += 32) {
    {
      const int r = tid >> 2, cg2 = (tid & 3) * 8;
      const float* ap = A + (long)(m0 + r) * lda + k0 + cg2;
      const float4 a0 = *(const float4*)ap;
      const float4 a1 = *(const float4*)(ap + 4);
      As2[cg2 + 0][r] = a0.x; As2[cg2 + 1][r] = a0.y; As2[cg2 + 2][r] = a0.z; As2[cg2 + 3][r] = a0.w;
      As2[cg2 + 4][r] = a1.x; As2[cg2 + 5][r] = a1.y; As2[cg2 + 6][r] = a1.z; As2[cg2 + 7][r] = a1.w;
    }
    {
      const int r = tid >> 2, cg2 = (tid & 3) * 8;
      float4 b0 = make_float4(0.f, 0.f, 0.f, 0.f);
      float4 b1 = make_float4(0.f, 0.f, 0.f, 0.f);
      if (n0 + r < N) {
        const float* bp = B + (long)(n0 + r) * ldb + boff + k0 + cg2;
        b0 = *(const float4*)bp;
        b1 = *(const float4*)(bp + 4);
      }
      Bs2[cg2 + 0][r] = b0.x; Bs2[cg2 + 1][r] = b0.y; Bs2[cg2 + 2][r] = b0.z; Bs2[cg2 + 3][r] = b0.w;
      Bs2[cg2 + 4][r] = b1.x; Bs2[cg2 + 5][r] = b1.y; Bs2[cg2 + 6][r] = b1.z; Bs2[cg2 + 7][r] = b1.w;
    }
    __syncthreads();
#pragma unroll
    for (int kk = 0; kk < 32; ++kk) {
      const float4 av = *(const float4*)&As2[kk][ty * 4];
      const float4 bv = *(const float4*)&Bs2[kk][tx * 4];
      acc[0][0] += av.x * bv.x; acc[0][1] += av.x * bv.y; acc[0][2] += av.x * bv.z; acc[0][3] += av.x * bv.w;
      acc[1][0] += av.y * bv.x; acc[1][1] += av.y * bv.y; acc[1][2] += av.y * bv.z; acc[1][3] += av.y * bv.w;
      acc[2][0] += av.z * bv.x; acc[2][1] += av.z * bv.y; acc[2][2] += av.z * bv.z; acc[2][3] += av.z * bv.w;
      acc[3][0] += av.w * bv.x; acc[3][1] += av.w * bv.y; acc[3][2] += av.w * bv.z; acc[3][3] += av.w * bv.w;
    }
    __syncthreads();
  }
#pragma unroll
  for (int i = 0; i < 4; ++i) {
    const int m = m0 + ty * 4 + i;
#pragma unroll
    for (int j = 0; j < 4; ++j) {
      const int n = n0 + tx * 4 + j;
      if (n < N) {
        float v = acc[i][j] + (bias ? bias[n] : 0.f);
        if (act == 1) v = tanhf(v);
        C[(long)m * ldc + n] = v;
      }
    }
  }
}

// ---------------------------------------------------------------- manual grid barrier (graph-capture-safe)
// All 256 blocks are co-resident (<=2 blocks/CU worth of resources on 256 CUs), so
// a monotonic-counter barrier cannot deadlock. Fences give device-scope (cross-XCD)
// release/acquire around the arrival counter.
__device__ __forceinline__ void grid_barrier(unsigned* __restrict__ bar, unsigned expected) {
  __threadfence();                 // release: write back dirty lines device-wide
  __syncthreads();
  if (threadIdx.x == 0) {
    atomicAdd(bar, 1u);            // device-scope arrival
    while (__hip_atomic_load(bar, __ATOMIC_ACQUIRE, __HIP_MEMORY_SCOPE_AGENT) < expected) {
      __builtin_amdgcn_s_sleep(4); // ~256-cycle backoff
    }
  }
  __syncthreads();
  __threadfence();                 // acquire: subsequent loads see fresh data
}

// ---------------------------------------------------------------- fused time loop (plain launch + manual barrier)
// 256 blocks x 256 threads. Per iteration t in [0,TT]:
//   phase A: blocks 0..63 attention(t) (t<TT); blocks 64..223 patch(t-1) (t>=1)
//   barrier
//   phase B: all 256 blocks gru(t) (t<TT)
//   barrier
// Patch weights (96 VGPR) and GRU weights (96 VGPR) hoisted OUT of the t-loop.
__global__ __launch_bounds__(256, 1) void loop_k(
    const float* __restrict__ ktil, const float* __restrict__ cbn,
    const float* __restrict__ vt, const float* __restrict__ locg,
    float* __restrict__ sbuf, float* __restrict__ rbuf,
    const float* __restrict__ w_write, const float* __restrict__ b_write,
    const float* __restrict__ w_loc, const int* __restrict__ amask,
    float* __restrict__ canvas, const float* __restrict__ gig,
    const float* __restrict__ w_ih, const float* __restrict__ w_hh,
    const float* __restrict__ b_hh, unsigned* __restrict__ bar) {
  __shared__ __align__(16) float smem[10048];   // ~40 KB, aliased per phase
  float* sm_act = smem;          // attn/patch staging: 8*1152
  float* sm_val = smem + 9216;   // patch results: 12*16
  float* sm_sc  = smem + 9408;   // attn scores: 64
  float* sm_s   = smem;          // gru: 8*576
  float* sm_r   = smem + 4608;   // gru: 8*576
  float* sm_g   = smem + 9216;   // gru results: 16*52

  const int blk = blockIdx.x, tid = threadIdx.x, lane = tid & 63;
  const bool is_attn = (blk < 64);
  const bool is_patch = (blk >= 64) && (blk < 224);
  unsigned nsync = 0;

  // ---- hoisted patch weights (blocks 64..223): rows tr*3..tr*3+2 of 12
  float4 wp[3][8];
  int p_rg = 0, p_bg = 0;
  if (is_patch) {
    const int g = blk - 64;
    p_bg = g & 3; p_rg = g >> 2;
    const int c = tid & 31, sl = tid >> 5, tr = sl & 3;
#pragma unroll
    for (int i = 0; i < 3; ++i) {
      const int rho = tr * 3 + i;
      const float* wsrc = (rho < 10) ? (w_write + (long)(p_rg * 10 + rho) * 1024 + c * 32)
                                     : (w_loc + (long)(rho - 10) * 1536 + c * 32);
#pragma unroll
      for (int j = 0; j < 8; ++j) wp[i][j] = *(const float4*)(wsrc + 4 * j);
    }
  }

  // ---- hoisted gru weights (all blocks): rows sl*3..sl*3+2 of 48
  float4 wg[3][8];
  const int g_dg = blk & 63, g_bg = blk >> 6;
  {
    const int c = tid & 15, sl = tid >> 4;
#pragma unroll
    for (int i = 0; i < 3; ++i) {
      const int rho = sl * 3 + i;
      const float* wsrc;
      if (rho < 24) {
        const int g2 = rho >> 3, di = rho & 7;
        wsrc = w_ih + (long)(g2 * 512 + g_dg * 8 + di) * 1024 + c * 32;   // r-half cols [0,512)
      } else {
        const int rh = rho - 24, g2 = rh >> 3, di = rh & 7;
        wsrc = w_hh + (long)(g2 * 512 + g_dg * 8 + di) * 512 + c * 32;
      }
#pragma unroll
      for (int j = 0; j < 8; ++j) wg[i][j] = *(const float4*)(wsrc + 4 * j);
    }
  }

  for (int t = 0; t <= TT; ++t) {
    const float* s_cur = sbuf + (t & 1) * (BB * DD);        // s_t
    float* r_cur = rbuf + (t & 1) * (BB * DD);              // r_t
    const float* r_prev = rbuf + ((t + 1) & 1) * (BB * DD); // r_{t-1}

    // ================= phase A =================
    if (is_attn) {
      if (t < TT) {
        const int b = blk, wrp = tid >> 6;
        const float4 sva = *(const float4*)(s_cur + (long)b * DD + lane * 8);
        const float4 svb = *(const float4*)(s_cur + (long)b * DD + lane * 8 + 4);
        for (int i = 0; i < 16; ++i) {
          const int n = wrp * 16 + i;
          const float* kp = ktil + ((long)(b * 64 + n)) * DD + lane * 8;
          const float4 k0 = *(const float4*)kp;
          const float4 k1 = *(const float4*)(kp + 4);
          float p = dot4(k0, sva) + dot4(k1, svb);
#pragma unroll
          for (int off = 32; off; off >>= 1) p += __shfl_xor(p, off);
          if (lane == 0) {
            float sc = p + cbn[b * 64 + n];
            if (amask[b * 64 + n] == 0) sc = -1e9f;
            sm_sc[n] = sc;
          }
        }
        __syncthreads();
        if (tid < 64) {
          const float v = sm_sc[tid];
          float m = v;
#pragma unroll
          for (int off = 32; off; off >>= 1) m = fmaxf(m, __shfl_xor(m, off));
          const float e = expf(v - m);
          float l2 = e;
#pragma unroll
          for (int off = 32; off; off >>= 1) l2 += __shfl_xor(l2, off);
          sm_sc[tid] = e / l2;
        }
        __syncthreads();
        float r0 = 0.f, r1 = 0.f;
        const float* vb = vt + (long)b * 64 * DD;
        for (int n = 0; n < 64; ++n) {
          const float a = sm_sc[n];
          r0 += a * vb[n * DD + tid];
          r1 += a * vb[n * DD + 256 + tid];
        }
        r_cur[b * DD + tid] = r0;
        r_cur[b * DD + 256 + tid] = r1;
      }
    } else if (is_patch) {
      if (t >= 1) {
        const int c = tid & 31, sl = tid >> 5;
        const int tr = sl & 3, bgsub = sl >> 2;
        for (int h = 0; h < 2; ++h) {
          __syncthreads();
          {
            const int b_i8 = tid >> 5, l = tid & 31;
            const int b = p_bg * 16 + h * 8 + b_i8;
            const float* sp = s_cur + (long)b * DD + l * 16;
            const float* rp = r_prev + (long)b * DD + l * 16;
            float* dsd = sm_act + b_i8 * 1152 + (l >> 1) * 36 + (l & 1) * 16;
            float* drd = sm_act + b_i8 * 1152 + (16 + (l >> 1)) * 36 + (l & 1) * 16;
#pragma unroll
            for (int jj = 0; jj < 4; ++jj) {
              *(float4*)(dsd + 4 * jj) = *(const float4*)(sp + 4 * jj);
              *(float4*)(drd + 4 * jj) = *(const float4*)(rp + 4 * jj);
            }
          }
          __syncthreads();
          for (int bi = 0; bi < 4; ++bi) {
            const int bl = bgsub * 4 + bi;
            const int babs = p_bg * 16 + h * 8 + bl;
            const float* ap = sm_act + bl * 1152 + c * 36;
            float a0 = 0.f, a1 = 0.f, a2 = 0.f;
#pragma unroll
            for (int j = 0; j < 8; ++j) {
              const float4 av = *(const float4*)(ap + 4 * j);
              a0 += dot4(wp[0][j], av);
              a1 += dot4(wp[1][j], av);
              a2 += dot4(wp[2][j], av);
            }
#pragma unroll
            for (int m = 1; m < 32; m <<= 1) {
              a0 += __shfl_xor(a0, m);
              a1 += __shfl_xor(a1, m);
              a2 += __shfl_xor(a2, m);
            }
            if (c == 0) {
              const int bslot = h * 8 + bl;
              const float av3[3] = {a0, a1, a2};
#pragma unroll
              for (int i = 0; i < 3; ++i) {
                const int rho = tr * 3 + i;
                float v = av3[i];
                if (rho >= 10) v += locg[babs * 2 + (rho - 10)];
                sm_val[rho * 16 + bslot] = v;
              }
            }
          }
        }
        __syncthreads();
        if (tid < 160) {
          const int ri = tid >> 4, bl2 = tid & 15;
          const int row = p_rg * 10 + ri;
          const int b = p_bg * 16 + bl2;
          const float val = sm_val[ri * 16 + bl2] + b_write[row];
          const float lx = sm_val[10 * 16 + bl2];
          const float ly = sm_val[11 * 16 + bl2];
          const int jx = min(127, max(0, (int)rintf(0.5f * (tanhf(lx) + 1.f) * 127.f)));
          const int iy = min(127, max(0, (int)rintf(0.5f * (tanhf(ly) + 1.f) * 127.f)));
          const int cc = row / 25, rem = row % 25, ki = rem / 5, kj = rem % 5;
          const int y = iy + ki - 2, x = jx + kj - 2;
          if (y >= 0 && y < 128 && x >= 0 && x < 128)
            atomicAdd(canvas + ((((long)b * 16 + cc) * 128 + y) * 128 + x), val);
        }
      }
    }

    grid_barrier(bar, ++nsync * 256u);

    // ================= phase B: gru(t) =================
    if (t < TT) {
      float* s_nxt = sbuf + ((t + 1) & 1) * (BB * DD);
      const int c = tid & 15, sl = tid >> 4;
      for (int h = 0; h < 2; ++h) {
        __syncthreads();
        {
          const int b_i8 = tid >> 5, l = tid & 31;
          const int b = g_bg * 16 + h * 8 + b_i8;
          const float* sp = s_cur + (long)b * DD + l * 16;
          const float* rp = r_cur + (long)b * DD + l * 16;
          float* dsd = sm_s + b_i8 * 576 + (l >> 1) * 36 + (l & 1) * 16;
          float* drd = sm_r + b_i8 * 576 + (l >> 1) * 36 + (l & 1) * 16;
#pragma unroll
          for (int jj = 0; jj < 4; ++jj) {
            *(float4*)(dsd + 4 * jj) = *(const float4*)(sp + 4 * jj);
            *(float4*)(drd + 4 * jj) = *(const float4*)(rp + 4 * jj);
          }
        }
        __syncthreads();
        const float* base = (sl < 8) ? sm_r : sm_s;
        for (int bl = 0; bl < 8; ++bl) {
          const float* ap = base + bl * 576 + c * 36;
          float a0 = 0.f, a1 = 0.f, a2 = 0.f;
#pragma unroll
          for (int j = 0; j < 8; ++j) {
            const float4 av = *(const float4*)(ap + 4 * j);
            a0 += dot4(wg[0][j], av);
            a1 += dot4(wg[1][j], av);
            a2 += dot4(wg[2][j], av);
          }
#pragma unroll
          for (int m = 1; m < 16; m <<= 1) {
            a0 += __shfl_xor(a0, m);
            a1 += __shfl_xor(a1, m);
            a2 += __shfl_xor(a2, m);
          }
          if (c == 0) {
            const int bslot = h * 8 + bl;
            sm_g[bslot * 52 + sl * 3 + 0] = a0;
            sm_g[bslot * 52 + sl * 3 + 1] = a1;
            sm_g[bslot * 52 + sl * 3 + 2] = a2;
          }
        }
      }
      __syncthreads();
      if (tid < 128) {
        const int b_i = tid >> 3, di = tid & 7;
        const int b = g_bg * 16 + b_i, d = g_dg * 8 + di;
        const float ir = sm_g[b_i * 52 + di]        + gig[b * 1536 + d];
        const float iz = sm_g[b_i * 52 + 8 + di]    + gig[b * 1536 + 512 + d];
        const float in = sm_g[b_i * 52 + 16 + di]   + gig[b * 1536 + 1024 + d];
        const float hr = sm_g[b_i * 52 + 24 + di]   + b_hh[d];
        const float hz = sm_g[b_i * 52 + 32 + di]   + b_hh[512 + d];
        const float hn = sm_g[b_i * 52 + 40 + di]   + b_hh[1024 + d];
        const float rg2 = 1.f / (1.f + expf(-(ir + hr)));
        const float zg = 1.f / (1.f + expf(-(iz + hz)));
        const float ng = tanhf(in + rg2 * hn);
        s_nxt[(long)b * DD + d] = (1.f - zg) * ng + zg * s_cur[(long)b * DD + d];
      }
    }

    grid_barrier(bar, ++nsync * 256u);
  }
}

// ---------------------------------------------------------------- launch
extern "C" void kernel_launch(void* const* d_in, const int* in_sizes, int n_in,
                              void* d_out, int out_size, void* d_ws, size_t ws_size,
                              hipStream_t stream) {
  const float* tok     = (const float*)d_in[0];
  const float* grep    = (const float*)d_in[1];
  const int*   amask   = (const int*)d_in[2];
  const float* w_init  = (const float*)d_in[3];
  const float* b_init  = (const float*)d_in[4];
  const float* wq      = (const float*)d_in[5];
  const float* bq      = (const float*)d_in[6];
  const float* wk      = (const float*)d_in[7];
  const float* bk      = (const float*)d_in[8];
  const float* wv      = (const float*)d_in[9];
  const float* bv      = (const float*)d_in[10];
  const float* w_ih    = (const float*)d_in[11];
  const float* b_ih    = (const float*)d_in[12];
  const float* w_hh    = (const float*)d_in[13];
  const float* b_hh    = (const float*)d_in[14];
  const float* w_write = (const float*)d_in[15];
  const float* b_write = (const float*)d_in[16];
  const float* w_loc   = (const float*)d_in[17];
  const float* b_loc   = (const float*)d_in[18];
  float* canvas = (float*)d_out;

  float* ws = (float*)d_ws;
  float* ktil = ws;                      // 64*64*512
  float* vtw  = ktil + 2097152;          // 64*64*512 (reused as Aqk split-K scratch first)
  float* Aqk  = vtw + 2097152;           // 512*512
  float* gig  = Aqk + 262144;            // 64*1536
  float* cbn  = gig + 98304;             // 64*64
  float* sbuf = cbn + 4096;              // 2*64*512
  float* rbuf = sbuf + 65536;            // 2*64*512
  float* locg = rbuf + 65536;            // 64*2
  float* kqb  = locg + 128;              // 512
  float* wkbq = kqb + 512;               // 512
  float* bqbk = wkbq + 512;              // 1
  unsigned* bar = (unsigned*)(bqbk + 64);// barrier counter (own line)

  zero_k<<<16384, 256, 0, stream>>>(canvas, 16777216 / 4);
  vecs_k<<<4, 256, 0, stream>>>(wq, bk, wk, bq, kqb, wkbq, bqbk, bar);
  // Aqk[e,m] = sum_a wq[a,e]*wk[a,m]  — split-K(4) into vtw scratch, then combine
  gemm128_k<<<dim3(4, 8, 4), 256, 0, stream>>>(wq, 512, 1, wk, 512, 0, 1,
                                               nullptr, vtw, 262144L, 512, 0, 128, 0);
  combine4_k<<<256, 256, 0, stream>>>(vtw, Aqk);
  // ktil = tok @ Aqk^T + kqb  AND  vt = tok @ wv^T + bv  in one 512-block launch
  gemm128_dual_k<<<dim3(32, 8, 2), 256, 0, stream>>>(tok, Aqk, kqb, ktil, wv, bv, vtw);
  // cbn = tok . wkbq + bqbk
  gemm_k<<<dim3(64, 1), 256, 0, stream>>>(tok, 512, 0, wkbq, 0, 0, 0, bqbk, cbn, 1, 4096, 1, 512, 0);
  // gig = grep @ w_ih[:,512:]^T + b_ih
  gemm_k<<<dim3(1, 24), 256, 0, stream>>>(grep, 512, 0, w_ih, 1024, 512, 0, b_ih, gig, 1536, 64, 1536, 512, 0);
  // s0 = tanh(grep @ w_init^T + b_init)
  gemm_k<<<dim3(1, 8), 256, 0, stream>>>(grep, 512, 0, w_init, 512, 0, 0, b_init, sbuf, 512, 64, 512, 512, 1);
  // locg = grep @ w_loc[0:2,1024:]^T + b_loc
  gemm_k<<<dim3(1, 1), 256, 0, stream>>>(grep, 512, 0, w_loc, 1536, 1024, 0, b_loc, locg, 2, 64, 2, 512, 0);

  // fused time loop: one plain kernel with manual grid barriers replaces 65 launches
  loop_k<<<256, 256, 0, stream>>>(ktil, cbn, vtw, locg, sbuf, rbuf, w_write, b_write,
                                  w_loc, amask, canvas, gig, w_ih, w_hh, b_hh, bar);
}

// Round 3
// 2753.579 us; speedup vs baseline: 3.7481x; 3.7481x over previous
//
#include <hip/hip_runtime.h>

#define BB 64      // batch
#define DD 512     // d_model = d_state = d_att
#define TT 32      // steps

__device__ __forceinline__ float dot4(const float4 a, const float4 b) {
  return a.x * b.x + a.y * b.y + a.z * b.z + a.w * b.w;
}

// coherent (agent-scope, relaxed) scalar load/store — bypasses stale L1/L2 without
// any cache invalidation. Used ONLY for the cross-block recurrent state (sbuf/rbuf).
__device__ __forceinline__ float cld(const float* p) {
  return __hip_atomic_load(p, __ATOMIC_RELAXED, __HIP_MEMORY_SCOPE_AGENT);
}
__device__ __forceinline__ void cst(float* p, float v) {
  __hip_atomic_store(p, v, __ATOMIC_RELAXED, __HIP_MEMORY_SCOPE_AGENT);
}

// ---------------------------------------------------------------- zero
__global__ void zero_k(float* __restrict__ out, int n4) {
  const int i = blockIdx.x * blockDim.x + threadIdx.x;
  if (i < n4) ((float4*)out)[i] = make_float4(0.f, 0.f, 0.f, 0.f);
}

// ---------------------------------------------------------------- small folded vectors (+ barrier reset)
__global__ void vecs_k(const float* __restrict__ wq, const float* __restrict__ bk,
                       const float* __restrict__ wk, const float* __restrict__ bq,
                       float* __restrict__ kqb, float* __restrict__ wkbq,
                       float* __restrict__ bqbk, unsigned* __restrict__ bar) {
  const int tid = threadIdx.x, bz = blockIdx.x;
  if (bz < 2) {
    const int d = bz * 256 + tid;
    float s = 0.f;
    for (int e = 0; e < DD; ++e) s += wq[e * DD + d] * bk[e];
    kqb[d] = s;
  } else {
    const int k = (bz - 2) * 256 + tid;
    float s = 0.f;
    for (int e = 0; e < DD; ++e) s += bq[e] * wk[e * DD + k];
    wkbq[k] = s;
    if (bz == 2 && tid == 0) {
      float t2 = 0.f;
      for (int e = 0; e < DD; ++e) t2 += bq[e] * bk[e];
      *bqbk = t2;
    }
    if (bz == 3 && tid == 0)
      __hip_atomic_store(bar, 0u, __ATOMIC_RELAXED, __HIP_MEMORY_SCOPE_AGENT);
  }
}

// ---------------------------------------------------------------- fast fp32 GEMM, 128x64 tile, 8x4 micro
__global__ __launch_bounds__(256) void gemm128_k(
    const float* __restrict__ A, int lda, int a_trans,
    const float* __restrict__ B, int ldb, int boff, int b_trans,
    const float* __restrict__ bias, float* __restrict__ C, long c_stride_z, int ldc,
    int kfrom, int klen, int act) {
  __shared__ __align__(16) float As[16][132];
  __shared__ __align__(16) float Bs[16][68];
  const int tid = threadIdx.x;
  const int tx = tid & 15, ty = tid >> 4;
  const int m0 = blockIdx.x * 128, n0 = blockIdx.y * 64;
  const int kbase = kfrom + blockIdx.z * klen;
  float* Ce = C + (long)blockIdx.z * c_stride_z;
  float acc[8][4];
#pragma unroll
  for (int i = 0; i < 8; ++i)
#pragma unroll
    for (int j = 0; j < 4; ++j) acc[i][j] = 0.f;

  for (int k0 = kbase; k0 < kbase + klen; k0 += 16) {
    if (!a_trans) {
      const int row = tid >> 1, half = tid & 1;
      const float* ap = A + (long)(m0 + row) * lda + k0 + half * 8;
      const float4 a0 = *(const float4*)ap;
      const float4 a1 = *(const float4*)(ap + 4);
      const int kb = half * 8;
      As[kb + 0][row] = a0.x; As[kb + 1][row] = a0.y; As[kb + 2][row] = a0.z; As[kb + 3][row] = a0.w;
      As[kb + 4][row] = a1.x; As[kb + 5][row] = a1.y; As[kb + 6][row] = a1.z; As[kb + 7][row] = a1.w;
    } else {
      const int kk = tid >> 4, mseg = tid & 15;
      const float* ap = A + (long)(k0 + kk) * lda + m0 + mseg * 8;
      *(float4*)&As[kk][mseg * 8] = *(const float4*)ap;
      *(float4*)&As[kk][mseg * 8 + 4] = *(const float4*)(ap + 4);
    }
    if (!b_trans) {
      const int n = tid >> 2, q = tid & 3;
      const float4 b0 = *(const float4*)(B + (long)(n0 + n) * ldb + boff + k0 + q * 4);
      Bs[q * 4 + 0][n] = b0.x; Bs[q * 4 + 1][n] = b0.y; Bs[q * 4 + 2][n] = b0.z; Bs[q * 4 + 3][n] = b0.w;
    } else {
      const int kk = tid >> 4, nq = tid & 15;
      *(float4*)&Bs[kk][nq * 4] = *(const float4*)(B + (long)(k0 + kk) * ldb + boff + n0 + nq * 4);
    }
    __syncthreads();
#pragma unroll
    for (int kk = 0; kk < 16; ++kk) {
      const float4 a0 = *(const float4*)&As[kk][ty * 8];
      const float4 a1 = *(const float4*)&As[kk][ty * 8 + 4];
      const float4 b0 = *(const float4*)&Bs[kk][tx * 4];
      const float am[8] = {a0.x, a0.y, a0.z, a0.w, a1.x, a1.y, a1.z, a1.w};
#pragma unroll
      for (int i = 0; i < 8; ++i) {
        acc[i][0] += am[i] * b0.x; acc[i][1] += am[i] * b0.y;
        acc[i][2] += am[i] * b0.z; acc[i][3] += am[i] * b0.w;
      }
    }
    __syncthreads();
  }
  float4 bv = make_float4(0.f, 0.f, 0.f, 0.f);
  if (bias) bv = *(const float4*)(bias + n0 + tx * 4);
#pragma unroll
  for (int i = 0; i < 8; ++i) {
    const int m = m0 + ty * 8 + i;
    float4 v = make_float4(acc[i][0] + bv.x, acc[i][1] + bv.y, acc[i][2] + bv.z, acc[i][3] + bv.w);
    if (act == 1) { v.x = tanhf(v.x); v.y = tanhf(v.y); v.z = tanhf(v.z); v.w = tanhf(v.w); }
    *(float4*)&Ce[(long)m * ldc + n0 + tx * 4] = v;
  }
}

// ---------------------------------------------------------------- dual big GEMM (2 blocks/CU)
__global__ __launch_bounds__(256) void gemm128_dual_k(
    const float* __restrict__ A,
    const float* __restrict__ B0, const float* __restrict__ bias0, float* __restrict__ C0,
    const float* __restrict__ B1, const float* __restrict__ bias1, float* __restrict__ C1) {
  __shared__ __align__(16) float As[16][132];
  __shared__ __align__(16) float Bs[16][68];
  const int tid = threadIdx.x;
  const int tx = tid & 15, ty = tid >> 4;
  const int m0 = blockIdx.x * 128, n0 = blockIdx.y * 64;
  const float* B = blockIdx.z ? B1 : B0;
  const float* bias = blockIdx.z ? bias1 : bias0;
  float* C = blockIdx.z ? C1 : C0;
  float acc[8][4];
#pragma unroll
  for (int i = 0; i < 8; ++i)
#pragma unroll
    for (int j = 0; j < 4; ++j) acc[i][j] = 0.f;

  for (int k0 = 0; k0 < 512; k0 += 16) {
    {
      const int row = tid >> 1, half = tid & 1;
      const float* ap = A + (long)(m0 + row) * 512 + k0 + half * 8;
      const float4 a0 = *(const float4*)ap;
      const float4 a1 = *(const float4*)(ap + 4);
      const int kb = half * 8;
      As[kb + 0][row] = a0.x; As[kb + 1][row] = a0.y; As[kb + 2][row] = a0.z; As[kb + 3][row] = a0.w;
      As[kb + 4][row] = a1.x; As[kb + 5][row] = a1.y; As[kb + 6][row] = a1.z; As[kb + 7][row] = a1.w;
    }
    {
      const int n = tid >> 2, q = tid & 3;
      const float4 b0 = *(const float4*)(B + (long)(n0 + n) * 512 + k0 + q * 4);
      Bs[q * 4 + 0][n] = b0.x; Bs[q * 4 + 1][n] = b0.y; Bs[q * 4 + 2][n] = b0.z; Bs[q * 4 + 3][n] = b0.w;
    }
    __syncthreads();
#pragma unroll
    for (int kk = 0; kk < 16; ++kk) {
      const float4 a0 = *(const float4*)&As[kk][ty * 8];
      const float4 a1 = *(const float4*)&As[kk][ty * 8 + 4];
      const float4 b0 = *(const float4*)&Bs[kk][tx * 4];
      const float am[8] = {a0.x, a0.y, a0.z, a0.w, a1.x, a1.y, a1.z, a1.w};
#pragma unroll
      for (int i = 0; i < 8; ++i) {
        acc[i][0] += am[i] * b0.x; acc[i][1] += am[i] * b0.y;
        acc[i][2] += am[i] * b0.z; acc[i][3] += am[i] * b0.w;
      }
    }
    __syncthreads();
  }
  const float4 bvv = *(const float4*)(bias + n0 + tx * 4);
#pragma unroll
  for (int i = 0; i < 8; ++i) {
    const int m = m0 + ty * 8 + i;
    float4 v = make_float4(acc[i][0] + bvv.x, acc[i][1] + bvv.y, acc[i][2] + bvv.z, acc[i][3] + bvv.w);
    *(float4*)&C[(long)m * 512 + n0 + tx * 4] = v;
  }
}

// sum 4 split-K partials (fixed order -> deterministic)
__global__ void combine4_k(const float* __restrict__ p, float* __restrict__ out) {
  const int i = blockIdx.x * blockDim.x + threadIdx.x;  // f4 index, 65536 total
  const float4 a = ((const float4*)p)[i];
  const float4 b = ((const float4*)p)[i + 65536];
  const float4 c = ((const float4*)p)[i + 131072];
  const float4 d = ((const float4*)p)[i + 196608];
  ((float4*)out)[i] = make_float4(a.x + b.x + c.x + d.x, a.y + b.y + c.y + d.y,
                                  a.z + b.z + c.z + d.z, a.w + b.w + c.w + d.w);
}

// ---------------------------------------------------------------- generic fp32 GEMM (kept for small shapes)
__global__ __launch_bounds__(256) void gemm_k(
    const float* __restrict__ A, int lda, int a_trans,
    const float* __restrict__ B, int ldb, int boff, int b_trans,
    const float* __restrict__ bias,
    float* __restrict__ C, int ldc, int M, int N, int K, int act) {
  __shared__ __align__(16) float As2[32][68];
  __shared__ __align__(16) float Bs2[32][68];
  const int tid = threadIdx.x;
  const int tx = tid & 15, ty = tid >> 4;
  const int m0 = blockIdx.x * 64, n0 = blockIdx.y * 64;
  float acc[4][4] = {};
  for (int k0 = 0; k0 < K; k0 += 32) {
    {
      const int r = tid >> 2, cg2 = (tid & 3) * 8;
      const float* ap = A + (long)(m0 + r) * lda + k0 + cg2;
      const float4 a0 = *(const float4*)ap;
      const float4 a1 = *(const float4*)(ap + 4);
      As2[cg2 + 0][r] = a0.x; As2[cg2 + 1][r] = a0.y; As2[cg2 + 2][r] = a0.z; As2[cg2 + 3][r] = a0.w;
      As2[cg2 + 4][r] = a1.x; As2[cg2 + 5][r] = a1.y; As2[cg2 + 6][r] = a1.z; As2[cg2 + 7][r] = a1.w;
    }
    {
      const int r = tid >> 2, cg2 = (tid & 3) * 8;
      float4 b0 = make_float4(0.f, 0.f, 0.f, 0.f);
      float4 b1 = make_float4(0.f, 0.f, 0.f, 0.f);
      if (n0 + r < N) {
        const float* bp = B + (long)(n0 + r) * ldb + boff + k0 + cg2;
        b0 = *(const float4*)bp;
        b1 = *(const float4*)(bp + 4);
      }
      Bs2[cg2 + 0][r] = b0.x; Bs2[cg2 + 1][r] = b0.y; Bs2[cg2 + 2][r] = b0.z; Bs2[cg2 + 3][r] = b0.w;
      Bs2[cg2 + 4][r] = b1.x; Bs2[cg2 + 5][r] = b1.y; Bs2[cg2 + 6][r] = b1.z; Bs2[cg2 + 7][r] = b1.w;
    }
    __syncthreads();
#pragma unroll
    for (int kk = 0; kk < 32; ++kk) {
      const float4 av = *(const float4*)&As2[kk][ty * 4];
      const float4 bv = *(const float4*)&Bs2[kk][tx * 4];
      acc[0][0] += av.x * bv.x; acc[0][1] += av.x * bv.y; acc[0][2] += av.x * bv.z; acc[0][3] += av.x * bv.w;
      acc[1][0] += av.y * bv.x; acc[1][1] += av.y * bv.y; acc[1][2] += av.y * bv.z; acc[1][3] += av.y * bv.w;
      acc[2][0] += av.z * bv.x; acc[2][1] += av.z * bv.y; acc[2][2] += av.z * bv.z; acc[2][3] += av.z * bv.w;
      acc[3][0] += av.w * bv.x; acc[3][1] += av.w * bv.y; acc[3][2] += av.w * bv.z; acc[3][3] += av.w * bv.w;
    }
    __syncthreads();
  }
#pragma unroll
  for (int i = 0; i < 4; ++i) {
    const int m = m0 + ty * 4 + i;
#pragma unroll
    for (int j = 0; j < 4; ++j) {
      const int n = n0 + tx * 4 + j;
      if (n < N) {
        float v = acc[i][j] + (bias ? bias[n] : 0.f);
        if (act == 1) v = tanhf(v);
        C[(long)m * ldc + n] = v;
      }
    }
  }
}

// ---------------------------------------------------------------- fence-free grid barrier
// All 256 blocks co-resident. __syncthreads() drains vmcnt(0) before s_barrier, so all
// coherent (sc-flagged) stores have reached the device coherence point before arrival.
// Arrival/poll are RELAXED — zero cache invalidation, so read-only data (ktil/vt/weights)
// stays hot in L1/L2 across the entire loop. Cross-block state uses cld/cst.
__device__ __forceinline__ void grid_barrier(unsigned* __restrict__ bar, unsigned expected) {
  __syncthreads();   // drains vmcnt -> coherent stores complete
  if (threadIdx.x == 0) {
    __hip_atomic_fetch_add(bar, 1u, __ATOMIC_RELAXED, __HIP_MEMORY_SCOPE_AGENT);
    while (__hip_atomic_load(bar, __ATOMIC_RELAXED, __HIP_MEMORY_SCOPE_AGENT) < expected) {
      __builtin_amdgcn_s_sleep(2);
    }
  }
  __syncthreads();
}

// ---------------------------------------------------------------- fused time loop
// 256 blocks x 256 threads. Per iteration t in [0,TT]:
//   phase A: blocks 0..63 attention(t) (t<TT); blocks 64..223 patch(t-1) (t>=1)
//   barrier
//   phase B: all 256 blocks gru(t) (t<TT)
//   barrier
// Patch weights (96 VGPR) and GRU weights (96 VGPR) hoisted OUT of the t-loop.
__global__ __launch_bounds__(256, 1) void loop_k(
    const float* __restrict__ ktil, const float* __restrict__ cbn,
    const float* __restrict__ vt, const float* __restrict__ locg,
    float* __restrict__ sbuf, float* __restrict__ rbuf,
    const float* __restrict__ w_write, const float* __restrict__ b_write,
    const float* __restrict__ w_loc, const int* __restrict__ amask,
    float* __restrict__ canvas, const float* __restrict__ gig,
    const float* __restrict__ w_ih, const float* __restrict__ w_hh,
    const float* __restrict__ b_hh, unsigned* __restrict__ bar) {
  __shared__ __align__(16) float smem[10048];   // ~40 KB, aliased per phase
  float* sm_act = smem;          // attn/patch staging: 8*1152
  float* sm_val = smem + 9216;   // patch results: 12*16
  float* sm_sc  = smem + 9408;   // attn scores: 64
  float* sm_s   = smem;          // gru: 8*576
  float* sm_r   = smem + 4608;   // gru: 8*576
  float* sm_g   = smem + 9216;   // gru results: 16*52

  const int blk = blockIdx.x, tid = threadIdx.x, lane = tid & 63;
  const bool is_attn = (blk < 64);
  const bool is_patch = (blk >= 64) && (blk < 224);
  unsigned nsync = 0;

  // ---- hoisted patch weights (blocks 64..223): rows tr*3..tr*3+2 of 12
  float4 wp[3][8];
  int p_rg = 0, p_bg = 0;
  if (is_patch) {
    const int g = blk - 64;
    p_bg = g & 3; p_rg = g >> 2;
    const int c = tid & 31, sl = tid >> 5, tr = sl & 3;
#pragma unroll
    for (int i = 0; i < 3; ++i) {
      const int rho = tr * 3 + i;
      const float* wsrc = (rho < 10) ? (w_write + (long)(p_rg * 10 + rho) * 1024 + c * 32)
                                     : (w_loc + (long)(rho - 10) * 1536 + c * 32);
#pragma unroll
      for (int j = 0; j < 8; ++j) wp[i][j] = *(const float4*)(wsrc + 4 * j);
    }
  }

  // ---- hoisted gru weights (all blocks): rows sl*3..sl*3+2 of 48
  float4 wg[3][8];
  const int g_dg = blk & 63, g_bg = blk >> 6;
  {
    const int c = tid & 15, sl = tid >> 4;
#pragma unroll
    for (int i = 0; i < 3; ++i) {
      const int rho = sl * 3 + i;
      const float* wsrc;
      if (rho < 24) {
        const int g2 = rho >> 3, di = rho & 7;
        wsrc = w_ih + (long)(g2 * 512 + g_dg * 8 + di) * 1024 + c * 32;   // r-half cols [0,512)
      } else {
        const int rh = rho - 24, g2 = rh >> 3, di = rh & 7;
        wsrc = w_hh + (long)(g2 * 512 + g_dg * 8 + di) * 512 + c * 32;
      }
#pragma unroll
      for (int j = 0; j < 8; ++j) wg[i][j] = *(const float4*)(wsrc + 4 * j);
    }
  }

  for (int t = 0; t <= TT; ++t) {
    const float* s_cur = sbuf + (t & 1) * (BB * DD);        // s_t
    float* r_cur = rbuf + (t & 1) * (BB * DD);              // r_t
    const float* r_prev = rbuf + ((t + 1) & 1) * (BB * DD); // r_{t-1}

    // ================= phase A =================
    if (is_attn) {
      if (t < TT) {
        const int b = blk, wrp = tid >> 6;
        const float* sp0 = s_cur + (long)b * DD + lane * 8;
        float4 sva, svb;
        sva.x = cld(sp0 + 0); sva.y = cld(sp0 + 1); sva.z = cld(sp0 + 2); sva.w = cld(sp0 + 3);
        svb.x = cld(sp0 + 4); svb.y = cld(sp0 + 5); svb.z = cld(sp0 + 6); svb.w = cld(sp0 + 7);
        for (int i = 0; i < 16; ++i) {
          const int n = wrp * 16 + i;
          const float* kp = ktil + ((long)(b * 64 + n)) * DD + lane * 8;
          const float4 k0 = *(const float4*)kp;
          const float4 k1 = *(const float4*)(kp + 4);
          float p = dot4(k0, sva) + dot4(k1, svb);
#pragma unroll
          for (int off = 32; off; off >>= 1) p += __shfl_xor(p, off);
          if (lane == 0) {
            float sc = p + cbn[b * 64 + n];
            if (amask[b * 64 + n] == 0) sc = -1e9f;
            sm_sc[n] = sc;
          }
        }
        __syncthreads();
        if (tid < 64) {
          const float v = sm_sc[tid];
          float m = v;
#pragma unroll
          for (int off = 32; off; off >>= 1) m = fmaxf(m, __shfl_xor(m, off));
          const float e = expf(v - m);
          float l2 = e;
#pragma unroll
          for (int off = 32; off; off >>= 1) l2 += __shfl_xor(l2, off);
          sm_sc[tid] = e / l2;
        }
        __syncthreads();
        float r0 = 0.f, r1 = 0.f;
        const float* vb = vt + (long)b * 64 * DD;
        for (int n = 0; n < 64; ++n) {
          const float a = sm_sc[n];
          r0 += a * vb[n * DD + tid];
          r1 += a * vb[n * DD + 256 + tid];
        }
        cst(r_cur + b * DD + tid, r0);
        cst(r_cur + b * DD + 256 + tid, r1);
      }
    } else if (is_patch) {
      if (t >= 1) {
        const int c = tid & 31, sl = tid >> 5;
        const int tr = sl & 3, bgsub = sl >> 2;
        for (int h = 0; h < 2; ++h) {
          __syncthreads();
          {
            const int b_i8 = tid >> 5, l = tid & 31;
            const int b = p_bg * 16 + h * 8 + b_i8;
            const float* sp = s_cur + (long)b * DD + l * 16;
            const float* rp = r_prev + (long)b * DD + l * 16;
            float* dsd = sm_act + b_i8 * 1152 + (l >> 1) * 36 + (l & 1) * 16;
            float* drd = sm_act + b_i8 * 1152 + (16 + (l >> 1)) * 36 + (l & 1) * 16;
#pragma unroll
            for (int jj = 0; jj < 4; ++jj) {
              float4 vs, vr;
              vs.x = cld(sp + 4 * jj + 0); vs.y = cld(sp + 4 * jj + 1);
              vs.z = cld(sp + 4 * jj + 2); vs.w = cld(sp + 4 * jj + 3);
              vr.x = cld(rp + 4 * jj + 0); vr.y = cld(rp + 4 * jj + 1);
              vr.z = cld(rp + 4 * jj + 2); vr.w = cld(rp + 4 * jj + 3);
              *(float4*)(dsd + 4 * jj) = vs;
              *(float4*)(drd + 4 * jj) = vr;
            }
          }
          __syncthreads();
          for (int bi = 0; bi < 4; ++bi) {
            const int bl = bgsub * 4 + bi;
            const int babs = p_bg * 16 + h * 8 + bl;
            const float* ap = sm_act + bl * 1152 + c * 36;
            float a0 = 0.f, a1 = 0.f, a2 = 0.f;
#pragma unroll
            for (int j = 0; j < 8; ++j) {
              const float4 av = *(const float4*)(ap + 4 * j);
              a0 += dot4(wp[0][j], av);
              a1 += dot4(wp[1][j], av);
              a2 += dot4(wp[2][j], av);
            }
#pragma unroll
            for (int m = 1; m < 32; m <<= 1) {
              a0 += __shfl_xor(a0, m);
              a1 += __shfl_xor(a1, m);
              a2 += __shfl_xor(a2, m);
            }
            if (c == 0) {
              const int bslot = h * 8 + bl;
              const float av3[3] = {a0, a1, a2};
#pragma unroll
              for (int i = 0; i < 3; ++i) {
                const int rho = tr * 3 + i;
                float v = av3[i];
                if (rho >= 10) v += locg[babs * 2 + (rho - 10)];
                sm_val[rho * 16 + bslot] = v;
              }
            }
          }
        }
        __syncthreads();
        if (tid < 160) {
          const int ri = tid >> 4, bl2 = tid & 15;
          const int row = p_rg * 10 + ri;
          const int b = p_bg * 16 + bl2;
          const float val = sm_val[ri * 16 + bl2] + b_write[row];
          const float lx = sm_val[10 * 16 + bl2];
          const float ly = sm_val[11 * 16 + bl2];
          const int jx = min(127, max(0, (int)rintf(0.5f * (tanhf(lx) + 1.f) * 127.f)));
          const int iy = min(127, max(0, (int)rintf(0.5f * (tanhf(ly) + 1.f) * 127.f)));
          const int cc = row / 25, rem = row % 25, ki = rem / 5, kj = rem % 5;
          const int y = iy + ki - 2, x = jx + kj - 2;
          if (y >= 0 && y < 128 && x >= 0 && x < 128)
            atomicAdd(canvas + ((((long)b * 16 + cc) * 128 + y) * 128 + x), val);
        }
      }
    }

    grid_barrier(bar, ++nsync * 256u);

    // ================= phase B: gru(t) =================
    if (t < TT) {
      float* s_nxt = sbuf + ((t + 1) & 1) * (BB * DD);
      const int c = tid & 15, sl = tid >> 4;
      for (int h = 0; h < 2; ++h) {
        __syncthreads();
        {
          const int b_i8 = tid >> 5, l = tid & 31;
          const int b = g_bg * 16 + h * 8 + b_i8;
          const float* sp = s_cur + (long)b * DD + l * 16;
          const float* rp = r_cur + (long)b * DD + l * 16;
          float* dsd = sm_s + b_i8 * 576 + (l >> 1) * 36 + (l & 1) * 16;
          float* drd = sm_r + b_i8 * 576 + (l >> 1) * 36 + (l & 1) * 16;
#pragma unroll
          for (int jj = 0; jj < 4; ++jj) {
            float4 vs, vr;
            vs.x = cld(sp + 4 * jj + 0); vs.y = cld(sp + 4 * jj + 1);
            vs.z = cld(sp + 4 * jj + 2); vs.w = cld(sp + 4 * jj + 3);
            vr.x = cld(rp + 4 * jj + 0); vr.y = cld(rp + 4 * jj + 1);
            vr.z = cld(rp + 4 * jj + 2); vr.w = cld(rp + 4 * jj + 3);
            *(float4*)(dsd + 4 * jj) = vs;
            *(float4*)(drd + 4 * jj) = vr;
          }
        }
        __syncthreads();
        const float* base = (sl < 8) ? sm_r : sm_s;
        for (int bl = 0; bl < 8; ++bl) {
          const float* ap = base + bl * 576 + c * 36;
          float a0 = 0.f, a1 = 0.f, a2 = 0.f;
#pragma unroll
          for (int j = 0; j < 8; ++j) {
            const float4 av = *(const float4*)(ap + 4 * j);
            a0 += dot4(wg[0][j], av);
            a1 += dot4(wg[1][j], av);
            a2 += dot4(wg[2][j], av);
          }
#pragma unroll
          for (int m = 1; m < 16; m <<= 1) {
            a0 += __shfl_xor(a0, m);
            a1 += __shfl_xor(a1, m);
            a2 += __shfl_xor(a2, m);
          }
          if (c == 0) {
            const int bslot = h * 8 + bl;
            sm_g[bslot * 52 + sl * 3 + 0] = a0;
            sm_g[bslot * 52 + sl * 3 + 1] = a1;
            sm_g[bslot * 52 + sl * 3 + 2] = a2;
          }
        }
      }
      __syncthreads();
      if (tid < 128) {
        const int b_i = tid >> 3, di = tid & 7;
        const int b = g_bg * 16 + b_i, d = g_dg * 8 + di;
        const float ir = sm_g[b_i * 52 + di]        + gig[b * 1536 + d];
        const float iz = sm_g[b_i * 52 + 8 + di]    + gig[b * 1536 + 512 + d];
        const float in = sm_g[b_i * 52 + 16 + di]   + gig[b * 1536 + 1024 + d];
        const float hr = sm_g[b_i * 52 + 24 + di]   + b_hh[d];
        const float hz = sm_g[b_i * 52 + 32 + di]   + b_hh[512 + d];
        const float hn = sm_g[b_i * 52 + 40 + di]   + b_hh[1024 + d];
        const float rg2 = 1.f / (1.f + expf(-(ir + hr)));
        const float zg = 1.f / (1.f + expf(-(iz + hz)));
        const float ng = tanhf(in + rg2 * hn);
        const float sprev = cld(s_cur + (long)b * DD + d);
        cst(s_nxt + (long)b * DD + d, (1.f - zg) * ng + zg * sprev);
      }
    }

    grid_barrier(bar, ++nsync * 256u);
  }
}

// ---------------------------------------------------------------- launch
extern "C" void kernel_launch(void* const* d_in, const int* in_sizes, int n_in,
                              void* d_out, int out_size, void* d_ws, size_t ws_size,
                              hipStream_t stream) {
  const float* tok     = (const float*)d_in[0];
  const float* grep    = (const float*)d_in[1];
  const int*   amask   = (const int*)d_in[2];
  const float* w_init  = (const float*)d_in[3];
  const float* b_init  = (const float*)d_in[4];
  const float* wq      = (const float*)d_in[5];
  const float* bq      = (const float*)d_in[6];
  const float* wk      = (const float*)d_in[7];
  const float* bk      = (const float*)d_in[8];
  const float* wv      = (const float*)d_in[9];
  const float* bv      = (const float*)d_in[10];
  const float* w_ih    = (const float*)d_in[11];
  const float* b_ih    = (const float*)d_in[12];
  const float* w_hh    = (const float*)d_in[13];
  const float* b_hh    = (const float*)d_in[14];
  const float* w_write = (const float*)d_in[15];
  const float* b_write = (const float*)d_in[16];
  const float* w_loc   = (const float*)d_in[17];
  const float* b_loc   = (const float*)d_in[18];
  float* canvas = (float*)d_out;

  float* ws = (float*)d_ws;
  float* ktil = ws;                      // 64*64*512
  float* vtw  = ktil + 2097152;          // 64*64*512 (reused as Aqk split-K scratch first)
  float* Aqk  = vtw + 2097152;           // 512*512
  float* gig  = Aqk + 262144;            // 64*1536
  float* cbn  = gig + 98304;             // 64*64
  float* sbuf = cbn + 4096;              // 2*64*512
  float* rbuf = sbuf + 65536;            // 2*64*512
  float* locg = rbuf + 65536;            // 64*2
  float* kqb  = locg + 128;              // 512
  float* wkbq = kqb + 512;               // 512
  float* bqbk = wkbq + 512;              // 1
  unsigned* bar = (unsigned*)(bqbk + 64);// barrier counter (own line)

  zero_k<<<16384, 256, 0, stream>>>(canvas, 16777216 / 4);
  vecs_k<<<4, 256, 0, stream>>>(wq, bk, wk, bq, kqb, wkbq, bqbk, bar);
  // Aqk[e,m] = sum_a wq[a,e]*wk[a,m]  — split-K(4) into vtw scratch, then combine
  gemm128_k<<<dim3(4, 8, 4), 256, 0, stream>>>(wq, 512, 1, wk, 512, 0, 1,
                                               nullptr, vtw, 262144L, 512, 0, 128, 0);
  combine4_k<<<256, 256, 0, stream>>>(vtw, Aqk);
  // ktil = tok @ Aqk^T + kqb  AND  vt = tok @ wv^T + bv  in one 512-block launch
  gemm128_dual_k<<<dim3(32, 8, 2), 256, 0, stream>>>(tok, Aqk, kqb, ktil, wv, bv, vtw);
  // cbn = tok . wkbq + bqbk
  gemm_k<<<dim3(64, 1), 256, 0, stream>>>(tok, 512, 0, wkbq, 0, 0, 0, bqbk, cbn, 1, 4096, 1, 512, 0);
  // gig = grep @ w_ih[:,512:]^T + b_ih
  gemm_k<<<dim3(1, 24), 256, 0, stream>>>(grep, 512, 0, w_ih, 1024, 512, 0, b_ih, gig, 1536, 64, 1536, 512, 0);
  // s0 = tanh(grep @ w_init^T + b_init)
  gemm_k<<<dim3(1, 8), 256, 0, stream>>>(grep, 512, 0, w_init, 512, 0, 0, b_init, sbuf, 512, 64, 512, 512, 1);
  // locg = grep @ w_loc[0:2,1024:]^T + b_loc
  gemm_k<<<dim3(1, 1), 256, 0, stream>>>(grep, 512, 0, w_loc, 1536, 1024, 0, b_loc, locg, 2, 64, 2, 512, 0);

  // fused time loop: one plain kernel with fence-free barriers replaces 65 launches
  loop_k<<<256, 256, 0, stream>>>(ktil, cbn, vtw, locg, sbuf, rbuf, w_write, b_write,
                                  w_loc, amask, canvas, gig, w_ih, w_hh, b_hh, bar);
}

// Round 4
// 2183.143 us; speedup vs baseline: 4.7274x; 1.2613x over previous
//
#include <hip/hip_runtime.h>

#define BB 64      // batch
#define DD 512     // d_model = d_state = d_att
#define TT 32      // steps

__device__ __forceinline__ float dot4(const float4 a, const float4 b) {
  return a.x * b.x + a.y * b.y + a.z * b.z + a.w * b.w;
}

// write-through (agent-scope) scalar store: makes recurrent-state writes visible at the
// device coherence point (LLC) so other XCDs' cache-miss fills observe them.
__device__ __forceinline__ void cst(float* p, float v) {
  __hip_atomic_store(p, v, __ATOMIC_RELAXED, __HIP_MEMORY_SCOPE_AGENT);
}

// ---------------------------------------------------------------- zero
__global__ void zero_k(float* __restrict__ out, int n4) {
  const int i = blockIdx.x * blockDim.x + threadIdx.x;
  if (i < n4) ((float4*)out)[i] = make_float4(0.f, 0.f, 0.f, 0.f);
}

// ---------------------------------------------------------------- small folded vectors (+ barrier reset)
// bar layout: [0,1024) group counters (16 used, stride 64 u32); [1024, 1024+8192) release words (256 used, stride 32 u32)
__global__ void vecs_k(const float* __restrict__ wq, const float* __restrict__ bk,
                       const float* __restrict__ wk, const float* __restrict__ bq,
                       float* __restrict__ kqb, float* __restrict__ wkbq,
                       float* __restrict__ bqbk, unsigned* __restrict__ bar) {
  const int tid = threadIdx.x, bz = blockIdx.x;
  if (bz < 2) {
    const int d = bz * 256 + tid;
    float s = 0.f;
    for (int e = 0; e < DD; ++e) s += wq[e * DD + d] * bk[e];
    kqb[d] = s;
  } else {
    const int k = (bz - 2) * 256 + tid;
    float s = 0.f;
    for (int e = 0; e < DD; ++e) s += bq[e] * wk[e * DD + k];
    wkbq[k] = s;
    if (bz == 2 && tid == 0) {
      float t2 = 0.f;
      for (int e = 0; e < DD; ++e) t2 += bq[e] * bk[e];
      *bqbk = t2;
    }
    if (bz == 3) {
      if (tid < 16)
        __hip_atomic_store(bar + tid * 64, 0u, __ATOMIC_RELAXED, __HIP_MEMORY_SCOPE_AGENT);
      __hip_atomic_store(bar + 1024 + tid * 32, 0u, __ATOMIC_RELAXED, __HIP_MEMORY_SCOPE_AGENT);
    }
  }
}

// ---------------------------------------------------------------- fast fp32 GEMM, 128x64 tile, 8x4 micro
__global__ __launch_bounds__(256) void gemm128_k(
    const float* __restrict__ A, int lda, int a_trans,
    const float* __restrict__ B, int ldb, int boff, int b_trans,
    const float* __restrict__ bias, float* __restrict__ C, long c_stride_z, int ldc,
    int kfrom, int klen, int act) {
  __shared__ __align__(16) float As[16][132];
  __shared__ __align__(16) float Bs[16][68];
  const int tid = threadIdx.x;
  const int tx = tid & 15, ty = tid >> 4;
  const int m0 = blockIdx.x * 128, n0 = blockIdx.y * 64;
  const int kbase = kfrom + blockIdx.z * klen;
  float* Ce = C + (long)blockIdx.z * c_stride_z;
  float acc[8][4];
#pragma unroll
  for (int i = 0; i < 8; ++i)
#pragma unroll
    for (int j = 0; j < 4; ++j) acc[i][j] = 0.f;

  for (int k0 = kbase; k0 < kbase + klen; k0 += 16) {
    if (!a_trans) {
      const int row = tid >> 1, half = tid & 1;
      const float* ap = A + (long)(m0 + row) * lda + k0 + half * 8;
      const float4 a0 = *(const float4*)ap;
      const float4 a1 = *(const float4*)(ap + 4);
      const int kb = half * 8;
      As[kb + 0][row] = a0.x; As[kb + 1][row] = a0.y; As[kb + 2][row] = a0.z; As[kb + 3][row] = a0.w;
      As[kb + 4][row] = a1.x; As[kb + 5][row] = a1.y; As[kb + 6][row] = a1.z; As[kb + 7][row] = a1.w;
    } else {
      const int kk = tid >> 4, mseg = tid & 15;
      const float* ap = A + (long)(k0 + kk) * lda + m0 + mseg * 8;
      *(float4*)&As[kk][mseg * 8] = *(const float4*)ap;
      *(float4*)&As[kk][mseg * 8 + 4] = *(const float4*)(ap + 4);
    }
    if (!b_trans) {
      const int n = tid >> 2, q = tid & 3;
      const float4 b0 = *(const float4*)(B + (long)(n0 + n) * ldb + boff + k0 + q * 4);
      Bs[q * 4 + 0][n] = b0.x; Bs[q * 4 + 1][n] = b0.y; Bs[q * 4 + 2][n] = b0.z; Bs[q * 4 + 3][n] = b0.w;
    } else {
      const int kk = tid >> 4, nq = tid & 15;
      *(float4*)&Bs[kk][nq * 4] = *(const float4*)(B + (long)(k0 + kk) * ldb + boff + n0 + nq * 4);
    }
    __syncthreads();
#pragma unroll
    for (int kk = 0; kk < 16; ++kk) {
      const float4 a0 = *(const float4*)&As[kk][ty * 8];
      const float4 a1 = *(const float4*)&As[kk][ty * 8 + 4];
      const float4 b0 = *(const float4*)&Bs[kk][tx * 4];
      const float am[8] = {a0.x, a0.y, a0.z, a0.w, a1.x, a1.y, a1.z, a1.w};
#pragma unroll
      for (int i = 0; i < 8; ++i) {
        acc[i][0] += am[i] * b0.x; acc[i][1] += am[i] * b0.y;
        acc[i][2] += am[i] * b0.z; acc[i][3] += am[i] * b0.w;
      }
    }
    __syncthreads();
  }
  float4 bv = make_float4(0.f, 0.f, 0.f, 0.f);
  if (bias) bv = *(const float4*)(bias + n0 + tx * 4);
#pragma unroll
  for (int i = 0; i < 8; ++i) {
    const int m = m0 + ty * 8 + i;
    float4 v = make_float4(acc[i][0] + bv.x, acc[i][1] + bv.y, acc[i][2] + bv.z, acc[i][3] + bv.w);
    if (act == 1) { v.x = tanhf(v.x); v.y = tanhf(v.y); v.z = tanhf(v.z); v.w = tanhf(v.w); }
    *(float4*)&Ce[(long)m * ldc + n0 + tx * 4] = v;
  }
}

// ---------------------------------------------------------------- dual big GEMM (2 blocks/CU)
__global__ __launch_bounds__(256) void gemm128_dual_k(
    const float* __restrict__ A,
    const float* __restrict__ B0, const float* __restrict__ bias0, float* __restrict__ C0,
    const float* __restrict__ B1, const float* __restrict__ bias1, float* __restrict__ C1) {
  __shared__ __align__(16) float As[16][132];
  __shared__ __align__(16) float Bs[16][68];
  const int tid = threadIdx.x;
  const int tx = tid & 15, ty = tid >> 4;
  const int m0 = blockIdx.x * 128, n0 = blockIdx.y * 64;
  const float* B = blockIdx.z ? B1 : B0;
  const float* bias = blockIdx.z ? bias1 : bias0;
  float* C = blockIdx.z ? C1 : C0;
  float acc[8][4];
#pragma unroll
  for (int i = 0; i < 8; ++i)
#pragma unroll
    for (int j = 0; j < 4; ++j) acc[i][j] = 0.f;

  for (int k0 = 0; k0 < 512; k0 += 16) {
    {
      const int row = tid >> 1, half = tid & 1;
      const float* ap = A + (long)(m0 + row) * 512 + k0 + half * 8;
      const float4 a0 = *(const float4*)ap;
      const float4 a1 = *(const float4*)(ap + 4);
      const int kb = half * 8;
      As[kb + 0][row] = a0.x; As[kb + 1][row] = a0.y; As[kb + 2][row] = a0.z; As[kb + 3][row] = a0.w;
      As[kb + 4][row] = a1.x; As[kb + 5][row] = a1.y; As[kb + 6][row] = a1.z; As[kb + 7][row] = a1.w;
    }
    {
      const int n = tid >> 2, q = tid & 3;
      const float4 b0 = *(const float4*)(B + (long)(n0 + n) * 512 + k0 + q * 4);
      Bs[q * 4 + 0][n] = b0.x; Bs[q * 4 + 1][n] = b0.y; Bs[q * 4 + 2][n] = b0.z; Bs[q * 4 + 3][n] = b0.w;
    }
    __syncthreads();
#pragma unroll
    for (int kk = 0; kk < 16; ++kk) {
      const float4 a0 = *(const float4*)&As[kk][ty * 8];
      const float4 a1 = *(const float4*)&As[kk][ty * 8 + 4];
      const float4 b0 = *(const float4*)&Bs[kk][tx * 4];
      const float am[8] = {a0.x, a0.y, a0.z, a0.w, a1.x, a1.y, a1.z, a1.w};
#pragma unroll
      for (int i = 0; i < 8; ++i) {
        acc[i][0] += am[i] * b0.x; acc[i][1] += am[i] * b0.y;
        acc[i][2] += am[i] * b0.z; acc[i][3] += am[i] * b0.w;
      }
    }
    __syncthreads();
  }
  const float4 bvv = *(const float4*)(bias + n0 + tx * 4);
#pragma unroll
  for (int i = 0; i < 8; ++i) {
    const int m = m0 + ty * 8 + i;
    float4 v = make_float4(acc[i][0] + bvv.x, acc[i][1] + bvv.y, acc[i][2] + bvv.z, acc[i][3] + bvv.w);
    *(float4*)&C[(long)m * 512 + n0 + tx * 4] = v;
  }
}

// sum 4 split-K partials (fixed order -> deterministic)
__global__ void combine4_k(const float* __restrict__ p, float* __restrict__ out) {
  const int i = blockIdx.x * blockDim.x + threadIdx.x;  // f4 index, 65536 total
  const float4 a = ((const float4*)p)[i];
  const float4 b = ((const float4*)p)[i + 65536];
  const float4 c = ((const float4*)p)[i + 131072];
  const float4 d = ((const float4*)p)[i + 196608];
  ((float4*)out)[i] = make_float4(a.x + b.x + c.x + d.x, a.y + b.y + c.y + d.y,
                                  a.z + b.z + c.z + d.z, a.w + b.w + c.w + d.w);
}

// ---------------------------------------------------------------- generic fp32 GEMM (kept for small shapes)
__global__ __launch_bounds__(256) void gemm_k(
    const float* __restrict__ A, int lda, int a_trans,
    const float* __restrict__ B, int ldb, int boff, int b_trans,
    const float* __restrict__ bias,
    float* __restrict__ C, int ldc, int M, int N, int K, int act) {
  __shared__ __align__(16) float As2[32][68];
  __shared__ __align__(16) float Bs2[32][68];
  const int tid = threadIdx.x;
  const int tx = tid & 15, ty = tid >> 4;
  const int m0 = blockIdx.x * 64, n0 = blockIdx.y * 64;
  float acc[4][4] = {};
  for (int k0 = 0; k0 < K; k0 += 32) {
    {
      const int r = tid >> 2, cg2 = (tid & 3) * 8;
      const float* ap = A + (long)(m0 + r) * lda + k0 + cg2;
      const float4 a0 = *(const float4*)ap;
      const float4 a1 = *(const float4*)(ap + 4);
      As2[cg2 + 0][r] = a0.x; As2[cg2 + 1][r] = a0.y; As2[cg2 + 2][r] = a0.z; As2[cg2 + 3][r] = a0.w;
      As2[cg2 + 4][r] = a1.x; As2[cg2 + 5][r] = a1.y; As2[cg2 + 6][r] = a1.z; As2[cg2 + 7][r] = a1.w;
    }
    {
      const int r = tid >> 2, cg2 = (tid & 3) * 8;
      float4 b0 = make_float4(0.f, 0.f, 0.f, 0.f);
      float4 b1 = make_float4(0.f, 0.f, 0.f, 0.f);
      if (n0 + r < N) {
        const float* bp = B + (long)(n0 + r) * ldb + boff + k0 + cg2;
        b0 = *(const float4*)bp;
        b1 = *(const float4*)(bp + 4);
      }
      Bs2[cg2 + 0][r] = b0.x; Bs2[cg2 + 1][r] = b0.y; Bs2[cg2 + 2][r] = b0.z; Bs2[cg2 + 3][r] = b0.w;
      Bs2[cg2 + 4][r] = b1.x; Bs2[cg2 + 5][r] = b1.y; Bs2[cg2 + 6][r] = b1.z; Bs2[cg2 + 7][r] = b1.w;
    }
    __syncthreads();
#pragma unroll
    for (int kk = 0; kk < 32; ++kk) {
      const float4 av = *(const float4*)&As2[kk][ty * 4];
      const float4 bv = *(const float4*)&Bs2[kk][tx * 4];
      acc[0][0] += av.x * bv.x; acc[0][1] += av.x * bv.y; acc[0][2] += av.x * bv.z; acc[0][3] += av.x * bv.w;
      acc[1][0] += av.y * bv.x; acc[1][1] += av.y * bv.y; acc[1][2] += av.y * bv.z; acc[1][3] += av.y * bv.w;
      acc[2][0] += av.z * bv.x; acc[2][1] += av.z * bv.y; acc[2][2] += av.z * bv.z; acc[2][3] += av.z * bv.w;
      acc[3][0] += av.w * bv.x; acc[3][1] += av.w * bv.y; acc[3][2] += av.w * bv.z; acc[3][3] += av.w * bv.w;
    }
    __syncthreads();
  }
#pragma unroll
  for (int i = 0; i < 4; ++i) {
    const int m = m0 + ty * 4 + i;
#pragma unroll
    for (int j = 0; j < 4; ++j) {
      const int n = n0 + tx * 4 + j;
      if (n < N) {
        float v = acc[i][j] + (bias ? bias[n] : 0.f);
        if (act == 1) v = tanhf(v);
        C[(long)m * ldc + n] = v;
      }
    }
  }
}

// ---------------------------------------------------------------- two-level grid barrier, contention-free polling
// Arrival: 16 group counters (one per 16 blocks, 256B apart). Block 0 aggregates with 16
// parallel lanes, then releases via 256 per-block words (128B apart). Each non-master block
// polls ONLY its own release line -> no hot-line fan-in, no RMW/poll interference.
// gctr = bar, rel = bar + 1024. All ops relaxed agent-scope (no cache invalidation).
__device__ __forceinline__ void grid_barrier(unsigned* __restrict__ bar, unsigned gen) {
  __syncthreads();   // per-wave vmcnt(0) drain: all prior write-through stores are at the LLC
  const int blk = blockIdx.x, tid = threadIdx.x;
  unsigned* gctr = bar;
  unsigned* rel = bar + 1024;
  if (blk == 0) {
    if (tid == 0)
      __hip_atomic_fetch_add(gctr, 1u, __ATOMIC_RELAXED, __HIP_MEMORY_SCOPE_AGENT);
    if (tid < 16) {
      while (__hip_atomic_load(gctr + tid * 64, __ATOMIC_RELAXED, __HIP_MEMORY_SCOPE_AGENT) < gen * 16u)
        __builtin_amdgcn_s_sleep(1);
    }
    __syncthreads();
    __hip_atomic_store(rel + tid * 32, gen, __ATOMIC_RELAXED, __HIP_MEMORY_SCOPE_AGENT);
  } else {
    if (tid == 0) {
      __hip_atomic_fetch_add(gctr + (blk >> 4) * 64, 1u, __ATOMIC_RELAXED, __HIP_MEMORY_SCOPE_AGENT);
      while (__hip_atomic_load(rel + blk * 32, __ATOMIC_RELAXED, __HIP_MEMORY_SCOPE_AGENT) < gen)
        __builtin_amdgcn_s_sleep(1);
    }
  }
  __syncthreads();
}

// ---------------------------------------------------------------- fused time loop
// Rotating step-indexed state buffers: s_t at sbuf + t*BB*DD (33 slots), r_t at rbuf + t*BB*DD
// (32 slots). Writers use write-through stores (cst); readers use PLAIN CACHED float4 loads —
// safe because each (step,address) is written exactly once before its first-ever access, so no
// stale cache line can exist. This restores L2 sharing for all staging reads.
__global__ __launch_bounds__(256, 1) void loop_k(
    const float* __restrict__ ktil, const float* __restrict__ cbn,
    const float* __restrict__ vt, const float* __restrict__ locg,
    float* __restrict__ sbuf, float* __restrict__ rbuf,
    const float* __restrict__ w_write, const float* __restrict__ b_write,
    const float* __restrict__ w_loc, const int* __restrict__ amask,
    float* __restrict__ canvas, const float* __restrict__ gig,
    const float* __restrict__ w_ih, const float* __restrict__ w_hh,
    const float* __restrict__ b_hh, unsigned* __restrict__ bar) {
  __shared__ __align__(16) float smem[10048];   // ~40 KB, aliased per phase
  float* sm_act = smem;          // attn/patch staging: 8*1152
  float* sm_val = smem + 9216;   // patch results: 12*16
  float* sm_sc  = smem + 9408;   // attn scores: 64
  float* sm_s   = smem;          // gru: 8*576
  float* sm_r   = smem + 4608;   // gru: 8*576
  float* sm_g   = smem + 9216;   // gru results: 16*52

  const int blk = blockIdx.x, tid = threadIdx.x, lane = tid & 63;
  const bool is_attn = (blk < 64);
  const bool is_patch = (blk >= 64) && (blk < 224);
  unsigned nsync = 0;

  // ---- hoisted patch weights (blocks 64..223): rows tr*3..tr*3+2 of 12
  float4 wp[3][8];
  int p_rg = 0, p_bg = 0;
  if (is_patch) {
    const int g = blk - 64;
    p_bg = g & 3; p_rg = g >> 2;
    const int c = tid & 31, sl = tid >> 5, tr = sl & 3;
#pragma unroll
    for (int i = 0; i < 3; ++i) {
      const int rho = tr * 3 + i;
      const float* wsrc = (rho < 10) ? (w_write + (long)(p_rg * 10 + rho) * 1024 + c * 32)
                                     : (w_loc + (long)(rho - 10) * 1536 + c * 32);
#pragma unroll
      for (int j = 0; j < 8; ++j) wp[i][j] = *(const float4*)(wsrc + 4 * j);
    }
  }

  // ---- hoisted gru weights (all blocks): rows sl*3..sl*3+2 of 48
  float4 wg[3][8];
  const int g_dg = blk & 63, g_bg = blk >> 6;
  {
    const int c = tid & 15, sl = tid >> 4;
#pragma unroll
    for (int i = 0; i < 3; ++i) {
      const int rho = sl * 3 + i;
      const float* wsrc;
      if (rho < 24) {
        const int g2 = rho >> 3, di = rho & 7;
        wsrc = w_ih + (long)(g2 * 512 + g_dg * 8 + di) * 1024 + c * 32;   // r-half cols [0,512)
      } else {
        const int rh = rho - 24, g2 = rh >> 3, di = rh & 7;
        wsrc = w_hh + (long)(g2 * 512 + g_dg * 8 + di) * 512 + c * 32;
      }
#pragma unroll
      for (int j = 0; j < 8; ++j) wg[i][j] = *(const float4*)(wsrc + 4 * j);
    }
  }

  for (int t = 0; t <= TT; ++t) {
    const float* s_cur = sbuf + (long)t * (BB * DD);        // s_t (slot t)
    float* r_cur = rbuf + (long)t * (BB * DD);              // r_t (slot t)
    const float* r_prev = r_cur - BB * DD;                  // r_{t-1} (valid for t>=1)

    // ================= phase A =================
    if (is_attn) {
      if (t < TT) {
        const int b = blk, wrp = tid >> 6;
        const float4 sva = *(const float4*)(s_cur + (long)b * DD + lane * 8);
        const float4 svb = *(const float4*)(s_cur + (long)b * DD + lane * 8 + 4);
        for (int i = 0; i < 16; ++i) {
          const int n = wrp * 16 + i;
          const float* kp = ktil + ((long)(b * 64 + n)) * DD + lane * 8;
          const float4 k0 = *(const float4*)kp;
          const float4 k1 = *(const float4*)(kp + 4);
          float p = dot4(k0, sva) + dot4(k1, svb);
#pragma unroll
          for (int off = 32; off; off >>= 1) p += __shfl_xor(p, off);
          if (lane == 0) {
            float sc = p + cbn[b * 64 + n];
            if (amask[b * 64 + n] == 0) sc = -1e9f;
            sm_sc[n] = sc;
          }
        }
        __syncthreads();
        if (tid < 64) {
          const float v = sm_sc[tid];
          float m = v;
#pragma unroll
          for (int off = 32; off; off >>= 1) m = fmaxf(m, __shfl_xor(m, off));
          const float e = expf(v - m);
          float l2 = e;
#pragma unroll
          for (int off = 32; off; off >>= 1) l2 += __shfl_xor(l2, off);
          sm_sc[tid] = e / l2;
        }
        __syncthreads();
        float r0 = 0.f, r1 = 0.f;
        const float* vb = vt + (long)b * 64 * DD;
        for (int n = 0; n < 64; ++n) {
          const float a = sm_sc[n];
          r0 += a * vb[n * DD + tid];
          r1 += a * vb[n * DD + 256 + tid];
        }
        cst(r_cur + b * DD + tid, r0);
        cst(r_cur + b * DD + 256 + tid, r1);
      }
    } else if (is_patch) {
      if (t >= 1) {
        const int c = tid & 31, sl = tid >> 5;
        const int tr = sl & 3, bgsub = sl >> 2;
        for (int h = 0; h < 2; ++h) {
          __syncthreads();
          {
            const int b_i8 = tid >> 5, l = tid & 31;
            const int b = p_bg * 16 + h * 8 + b_i8;
            const float* sp = s_cur + (long)b * DD + l * 16;
            const float* rp = r_prev + (long)b * DD + l * 16;
            float* dsd = sm_act + b_i8 * 1152 + (l >> 1) * 36 + (l & 1) * 16;
            float* drd = sm_act + b_i8 * 1152 + (16 + (l >> 1)) * 36 + (l & 1) * 16;
#pragma unroll
            for (int jj = 0; jj < 4; ++jj) {
              *(float4*)(dsd + 4 * jj) = *(const float4*)(sp + 4 * jj);
              *(float4*)(drd + 4 * jj) = *(const float4*)(rp + 4 * jj);
            }
          }
          __syncthreads();
          for (int bi = 0; bi < 4; ++bi) {
            const int bl = bgsub * 4 + bi;
            const int babs = p_bg * 16 + h * 8 + bl;
            const float* ap = sm_act + bl * 1152 + c * 36;
            float a0 = 0.f, a1 = 0.f, a2 = 0.f;
#pragma unroll
            for (int j = 0; j < 8; ++j) {
              const float4 av = *(const float4*)(ap + 4 * j);
              a0 += dot4(wp[0][j], av);
              a1 += dot4(wp[1][j], av);
              a2 += dot4(wp[2][j], av);
            }
#pragma unroll
            for (int m = 1; m < 32; m <<= 1) {
              a0 += __shfl_xor(a0, m);
              a1 += __shfl_xor(a1, m);
              a2 += __shfl_xor(a2, m);
            }
            if (c == 0) {
              const int bslot = h * 8 + bl;
              const float av3[3] = {a0, a1, a2};
#pragma unroll
              for (int i = 0; i < 3; ++i) {
                const int rho = tr * 3 + i;
                float v = av3[i];
                if (rho >= 10) v += locg[babs * 2 + (rho - 10)];
                sm_val[rho * 16 + bslot] = v;
              }
            }
          }
        }
        __syncthreads();
        if (tid < 160) {
          const int ri = tid >> 4, bl2 = tid & 15;
          const int row = p_rg * 10 + ri;
          const int b = p_bg * 16 + bl2;
          const float val = sm_val[ri * 16 + bl2] + b_write[row];
          const float lx = sm_val[10 * 16 + bl2];
          const float ly = sm_val[11 * 16 + bl2];
          const int jx = min(127, max(0, (int)rintf(0.5f * (tanhf(lx) + 1.f) * 127.f)));
          const int iy = min(127, max(0, (int)rintf(0.5f * (tanhf(ly) + 1.f) * 127.f)));
          const int cc = row / 25, rem = row % 25, ki = rem / 5, kj = rem % 5;
          const int y = iy + ki - 2, x = jx + kj - 2;
          if (y >= 0 && y < 128 && x >= 0 && x < 128)
            atomicAdd(canvas + ((((long)b * 16 + cc) * 128 + y) * 128 + x), val);
        }
      }
    }

    grid_barrier(bar, ++nsync);

    // ================= phase B: gru(t) =================
    if (t >= TT) break;   // after last patch: done (skip dead final barrier)

    {
      float* s_nxt = sbuf + (long)(t + 1) * (BB * DD);
      const int c = tid & 15, sl = tid >> 4;
      for (int h = 0; h < 2; ++h) {
        __syncthreads();
        {
          const int b_i8 = tid >> 5, l = tid & 31;
          const int b = g_bg * 16 + h * 8 + b_i8;
          const float* sp = s_cur + (long)b * DD + l * 16;
          const float* rp = r_cur + (long)b * DD + l * 16;
          float* dsd = sm_s + b_i8 * 576 + (l >> 1) * 36 + (l & 1) * 16;
          float* drd = sm_r + b_i8 * 576 + (l >> 1) * 36 + (l & 1) * 16;
#pragma unroll
          for (int jj = 0; jj < 4; ++jj) {
            *(float4*)(dsd + 4 * jj) = *(const float4*)(sp + 4 * jj);
            *(float4*)(drd + 4 * jj) = *(const float4*)(rp + 4 * jj);
          }
        }
        __syncthreads();
        const float* base = (sl < 8) ? sm_r : sm_s;
        for (int bl = 0; bl < 8; ++bl) {
          const float* ap = base + bl * 576 + c * 36;
          float a0 = 0.f, a1 = 0.f, a2 = 0.f;
#pragma unroll
          for (int j = 0; j < 8; ++j) {
            const float4 av = *(const float4*)(ap + 4 * j);
            a0 += dot4(wg[0][j], av);
            a1 += dot4(wg[1][j], av);
            a2 += dot4(wg[2][j], av);
          }
#pragma unroll
          for (int m = 1; m < 16; m <<= 1) {
            a0 += __shfl_xor(a0, m);
            a1 += __shfl_xor(a1, m);
            a2 += __shfl_xor(a2, m);
          }
          if (c == 0) {
            const int bslot = h * 8 + bl;
            sm_g[bslot * 52 + sl * 3 + 0] = a0;
            sm_g[bslot * 52 + sl * 3 + 1] = a1;
            sm_g[bslot * 52 + sl * 3 + 2] = a2;
          }
        }
      }
      __syncthreads();
      if (tid < 128) {
        const int b_i = tid >> 3, di = tid & 7;
        const int b = g_bg * 16 + b_i, d = g_dg * 8 + di;
        const float ir = sm_g[b_i * 52 + di]        + gig[b * 1536 + d];
        const float iz = sm_g[b_i * 52 + 8 + di]    + gig[b * 1536 + 512 + d];
        const float in = sm_g[b_i * 52 + 16 + di]   + gig[b * 1536 + 1024 + d];
        const float hr = sm_g[b_i * 52 + 24 + di]   + b_hh[d];
        const float hz = sm_g[b_i * 52 + 32 + di]   + b_hh[512 + d];
        const float hn = sm_g[b_i * 52 + 40 + di]   + b_hh[1024 + d];
        const float rg2 = 1.f / (1.f + expf(-(ir + hr)));
        const float zg = 1.f / (1.f + expf(-(iz + hz)));
        const float ng = tanhf(in + rg2 * hn);
        const float sprev = s_cur[(long)b * DD + d];
        cst(s_nxt + (long)b * DD + d, (1.f - zg) * ng + zg * sprev);
      }
    }

    grid_barrier(bar, ++nsync);
  }
}

// ---------------------------------------------------------------- launch
extern "C" void kernel_launch(void* const* d_in, const int* in_sizes, int n_in,
                              void* d_out, int out_size, void* d_ws, size_t ws_size,
                              hipStream_t stream) {
  const float* tok     = (const float*)d_in[0];
  const float* grep    = (const float*)d_in[1];
  const int*   amask   = (const int*)d_in[2];
  const float* w_init  = (const float*)d_in[3];
  const float* b_init  = (const float*)d_in[4];
  const float* wq      = (const float*)d_in[5];
  const float* bq      = (const float*)d_in[6];
  const float* wk      = (const float*)d_in[7];
  const float* bk      = (const float*)d_in[8];
  const float* wv      = (const float*)d_in[9];
  const float* bv      = (const float*)d_in[10];
  const float* w_ih    = (const float*)d_in[11];
  const float* b_ih    = (const float*)d_in[12];
  const float* w_hh    = (const float*)d_in[13];
  const float* b_hh    = (const float*)d_in[14];
  const float* w_write = (const float*)d_in[15];
  const float* b_write = (const float*)d_in[16];
  const float* w_loc   = (const float*)d_in[17];
  const float* b_loc   = (const float*)d_in[18];
  float* canvas = (float*)d_out;

  float* ws = (float*)d_ws;
  float* ktil = ws;                      // 2,097,152
  float* vtw  = ktil + 2097152;          // 2,097,152 (reused as Aqk split-K scratch first)
  float* Aqk  = vtw + 2097152;           // 262,144
  float* gig  = Aqk + 262144;            // 98,304
  float* cbn  = gig + 98304;             // 4,096
  float* sbuf = cbn + 4096;              // 33 slots * 32768 = 1,081,344 (s_0..s_32)
  float* rbuf = sbuf + 1081344;          // 32 slots * 32768 = 1,048,576 (r_0..r_31)
  float* locg = rbuf + 1048576;          // 128
  float* kqb  = locg + 128;              // 512
  float* wkbq = kqb + 512;               // 512
  float* bqbk = wkbq + 512;              // 64 (pad)
  unsigned* bar = (unsigned*)(bqbk + 64);// 16 group ctrs (stride 64) + 256 release words (stride 32)

  zero_k<<<16384, 256, 0, stream>>>(canvas, 16777216 / 4);
  vecs_k<<<4, 256, 0, stream>>>(wq, bk, wk, bq, kqb, wkbq, bqbk, bar);
  // Aqk[e,m] = sum_a wq[a,e]*wk[a,m]  — split-K(4) into vtw scratch, then combine
  gemm128_k<<<dim3(4, 8, 4), 256, 0, stream>>>(wq, 512, 1, wk, 512, 0, 1,
                                               nullptr, vtw, 262144L, 512, 0, 128, 0);
  combine4_k<<<256, 256, 0, stream>>>(vtw, Aqk);
  // ktil = tok @ Aqk^T + kqb  AND  vt = tok @ wv^T + bv  in one 512-block launch
  gemm128_dual_k<<<dim3(32, 8, 2), 256, 0, stream>>>(tok, Aqk, kqb, ktil, wv, bv, vtw);
  // cbn = tok . wkbq + bqbk
  gemm_k<<<dim3(64, 1), 256, 0, stream>>>(tok, 512, 0, wkbq, 0, 0, 0, bqbk, cbn, 1, 4096, 1, 512, 0);
  // gig = grep @ w_ih[:,512:]^T + b_ih
  gemm_k<<<dim3(1, 24), 256, 0, stream>>>(grep, 512, 0, w_ih, 1024, 512, 0, b_ih, gig, 1536, 64, 1536, 512, 0);
  // s0 = tanh(grep @ w_init^T + b_init)  -> sbuf slot 0
  gemm_k<<<dim3(1, 8), 256, 0, stream>>>(grep, 512, 0, w_init, 512, 0, 0, b_init, sbuf, 512, 64, 512, 512, 1);
  // locg = grep @ w_loc[0:2,1024:]^T + b_loc
  gemm_k<<<dim3(1, 1), 256, 0, stream>>>(grep, 512, 0, w_loc, 1536, 1024, 0, b_loc, locg, 2, 64, 2, 512, 0);

  // fused time loop: one plain kernel, rotating state buffers, two-level barrier
  loop_k<<<256, 256, 0, stream>>>(ktil, cbn, vtw, locg, sbuf, rbuf, w_write, b_write,
                                  w_loc, amask, canvas, gig, w_ih, w_hh, b_hh, bar);
}

// Round 5
// 1133.777 us; speedup vs baseline: 9.1029x; 1.9255x over previous
//
#include <hip/hip_runtime.h>

#define BB 64      // batch
#define DD 512     // d_model = d_state = d_att
#define TT 32      // steps

__device__ __forceinline__ float dot4(const float4 a, const float4 b) {
  return a.x * b.x + a.y * b.y + a.z * b.z + a.w * b.w;
}

// write-through (agent-scope) scalar store: makes recurrent-state writes visible at the
// device coherence point (LLC) so other XCDs' cache-miss fills observe them.
__device__ __forceinline__ void cst(float* p, float v) {
  __hip_atomic_store(p, v, __ATOMIC_RELAXED, __HIP_MEMORY_SCOPE_AGENT);
}

// ---------------------------------------------------------------- zero
__global__ void zero_k(float* __restrict__ out, int n4) {
  const int i = blockIdx.x * blockDim.x + threadIdx.x;
  if (i < n4) ((float4*)out)[i] = make_float4(0.f, 0.f, 0.f, 0.f);
}

// ---------------------------------------------------------------- small folded vectors (+ barrier reset)
// bar layout: [0,1024) group counters (16 used, stride 64 u32); [1024, 1024+8192) release words (256 used, stride 32 u32)
__global__ void vecs_k(const float* __restrict__ wq, const float* __restrict__ bk,
                       const float* __restrict__ wk, const float* __restrict__ bq,
                       float* __restrict__ kqb, float* __restrict__ wkbq,
                       float* __restrict__ bqbk, unsigned* __restrict__ bar) {
  const int tid = threadIdx.x, bz = blockIdx.x;
  if (bz < 2) {
    const int d = bz * 256 + tid;
    float s = 0.f;
    for (int e = 0; e < DD; ++e) s += wq[e * DD + d] * bk[e];
    kqb[d] = s;
  } else {
    const int k = (bz - 2) * 256 + tid;
    float s = 0.f;
    for (int e = 0; e < DD; ++e) s += bq[e] * wk[e * DD + k];
    wkbq[k] = s;
    if (bz == 2 && tid == 0) {
      float t2 = 0.f;
      for (int e = 0; e < DD; ++e) t2 += bq[e] * bk[e];
      *bqbk = t2;
    }
    if (bz == 3) {
      if (tid < 16)
        __hip_atomic_store(bar + tid * 64, 0u, __ATOMIC_RELAXED, __HIP_MEMORY_SCOPE_AGENT);
      __hip_atomic_store(bar + 1024 + tid * 32, 0u, __ATOMIC_RELAXED, __HIP_MEMORY_SCOPE_AGENT);
    }
  }
}

// ---------------------------------------------------------------- fast fp32 GEMM, 128x64 tile, 8x4 micro
__global__ __launch_bounds__(256) void gemm128_k(
    const float* __restrict__ A, int lda, int a_trans,
    const float* __restrict__ B, int ldb, int boff, int b_trans,
    const float* __restrict__ bias, float* __restrict__ C, long c_stride_z, int ldc,
    int kfrom, int klen, int act) {
  __shared__ __align__(16) float As[16][132];
  __shared__ __align__(16) float Bs[16][68];
  const int tid = threadIdx.x;
  const int tx = tid & 15, ty = tid >> 4;
  const int m0 = blockIdx.x * 128, n0 = blockIdx.y * 64;
  const int kbase = kfrom + blockIdx.z * klen;
  float* Ce = C + (long)blockIdx.z * c_stride_z;
  float acc[8][4];
#pragma unroll
  for (int i = 0; i < 8; ++i)
#pragma unroll
    for (int j = 0; j < 4; ++j) acc[i][j] = 0.f;

  for (int k0 = kbase; k0 < kbase + klen; k0 += 16) {
    if (!a_trans) {
      const int row = tid >> 1, half = tid & 1;
      const float* ap = A + (long)(m0 + row) * lda + k0 + half * 8;
      const float4 a0 = *(const float4*)ap;
      const float4 a1 = *(const float4*)(ap + 4);
      const int kb = half * 8;
      As[kb + 0][row] = a0.x; As[kb + 1][row] = a0.y; As[kb + 2][row] = a0.z; As[kb + 3][row] = a0.w;
      As[kb + 4][row] = a1.x; As[kb + 5][row] = a1.y; As[kb + 6][row] = a1.z; As[kb + 7][row] = a1.w;
    } else {
      const int kk = tid >> 4, mseg = tid & 15;
      const float* ap = A + (long)(k0 + kk) * lda + m0 + mseg * 8;
      *(float4*)&As[kk][mseg * 8] = *(const float4*)ap;
      *(float4*)&As[kk][mseg * 8 + 4] = *(const float4*)(ap + 4);
    }
    if (!b_trans) {
      const int n = tid >> 2, q = tid & 3;
      const float4 b0 = *(const float4*)(B + (long)(n0 + n) * ldb + boff + k0 + q * 4);
      Bs[q * 4 + 0][n] = b0.x; Bs[q * 4 + 1][n] = b0.y; Bs[q * 4 + 2][n] = b0.z; Bs[q * 4 + 3][n] = b0.w;
    } else {
      const int kk = tid >> 4, nq = tid & 15;
      *(float4*)&Bs[kk][nq * 4] = *(const float4*)(B + (long)(k0 + kk) * ldb + boff + n0 + nq * 4);
    }
    __syncthreads();
#pragma unroll
    for (int kk = 0; kk < 16; ++kk) {
      const float4 a0 = *(const float4*)&As[kk][ty * 8];
      const float4 a1 = *(const float4*)&As[kk][ty * 8 + 4];
      const float4 b0 = *(const float4*)&Bs[kk][tx * 4];
      const float am[8] = {a0.x, a0.y, a0.z, a0.w, a1.x, a1.y, a1.z, a1.w};
#pragma unroll
      for (int i = 0; i < 8; ++i) {
        acc[i][0] += am[i] * b0.x; acc[i][1] += am[i] * b0.y;
        acc[i][2] += am[i] * b0.z; acc[i][3] += am[i] * b0.w;
      }
    }
    __syncthreads();
  }
  float4 bv = make_float4(0.f, 0.f, 0.f, 0.f);
  if (bias) bv = *(const float4*)(bias + n0 + tx * 4);
#pragma unroll
  for (int i = 0; i < 8; ++i) {
    const int m = m0 + ty * 8 + i;
    float4 v = make_float4(acc[i][0] + bv.x, acc[i][1] + bv.y, acc[i][2] + bv.z, acc[i][3] + bv.w);
    if (act == 1) { v.x = tanhf(v.x); v.y = tanhf(v.y); v.z = tanhf(v.z); v.w = tanhf(v.w); }
    *(float4*)&Ce[(long)m * ldc + n0 + tx * 4] = v;
  }
}

// ---------------------------------------------------------------- dual big GEMM (2 blocks/CU)
__global__ __launch_bounds__(256) void gemm128_dual_k(
    const float* __restrict__ A,
    const float* __restrict__ B0, const float* __restrict__ bias0, float* __restrict__ C0,
    const float* __restrict__ B1, const float* __restrict__ bias1, float* __restrict__ C1) {
  __shared__ __align__(16) float As[16][132];
  __shared__ __align__(16) float Bs[16][68];
  const int tid = threadIdx.x;
  const int tx = tid & 15, ty = tid >> 4;
  const int m0 = blockIdx.x * 128, n0 = blockIdx.y * 64;
  const float* B = blockIdx.z ? B1 : B0;
  const float* bias = blockIdx.z ? bias1 : bias0;
  float* C = blockIdx.z ? C1 : C0;
  float acc[8][4];
#pragma unroll
  for (int i = 0; i < 8; ++i)
#pragma unroll
    for (int j = 0; j < 4; ++j) acc[i][j] = 0.f;

  for (int k0 = 0; k0 < 512; k0 += 16) {
    {
      const int row = tid >> 1, half = tid & 1;
      const float* ap = A + (long)(m0 + row) * 512 + k0 + half * 8;
      const float4 a0 = *(const float4*)ap;
      const float4 a1 = *(const float4*)(ap + 4);
      const int kb = half * 8;
      As[kb + 0][row] = a0.x; As[kb + 1][row] = a0.y; As[kb + 2][row] = a0.z; As[kb + 3][row] = a0.w;
      As[kb + 4][row] = a1.x; As[kb + 5][row] = a1.y; As[kb + 6][row] = a1.z; As[kb + 7][row] = a1.w;
    }
    {
      const int n = tid >> 2, q = tid & 3;
      const float4 b0 = *(const float4*)(B + (long)(n0 + n) * 512 + k0 + q * 4);
      Bs[q * 4 + 0][n] = b0.x; Bs[q * 4 + 1][n] = b0.y; Bs[q * 4 + 2][n] = b0.z; Bs[q * 4 + 3][n] = b0.w;
    }
    __syncthreads();
#pragma unroll
    for (int kk = 0; kk < 16; ++kk) {
      const float4 a0 = *(const float4*)&As[kk][ty * 8];
      const float4 a1 = *(const float4*)&As[kk][ty * 8 + 4];
      const float4 b0 = *(const float4*)&Bs[kk][tx * 4];
      const float am[8] = {a0.x, a0.y, a0.z, a0.w, a1.x, a1.y, a1.z, a1.w};
#pragma unroll
      for (int i = 0; i < 8; ++i) {
        acc[i][0] += am[i] * b0.x; acc[i][1] += am[i] * b0.y;
        acc[i][2] += am[i] * b0.z; acc[i][3] += am[i] * b0.w;
      }
    }
    __syncthreads();
  }
  const float4 bvv = *(const float4*)(bias + n0 + tx * 4);
#pragma unroll
  for (int i = 0; i < 8; ++i) {
    const int m = m0 + ty * 8 + i;
    float4 v = make_float4(acc[i][0] + bvv.x, acc[i][1] + bvv.y, acc[i][2] + bvv.z, acc[i][3] + bvv.w);
    *(float4*)&C[(long)m * 512 + n0 + tx * 4] = v;
  }
}

// sum 4 split-K partials (fixed order -> deterministic)
__global__ void combine4_k(const float* __restrict__ p, float* __restrict__ out) {
  const int i = blockIdx.x * blockDim.x + threadIdx.x;  // f4 index, 65536 total
  const float4 a = ((const float4*)p)[i];
  const float4 b = ((const float4*)p)[i + 65536];
  const float4 c = ((const float4*)p)[i + 131072];
  const float4 d = ((const float4*)p)[i + 196608];
  ((float4*)out)[i] = make_float4(a.x + b.x + c.x + d.x, a.y + b.y + c.y + d.y,
                                  a.z + b.z + c.z + d.z, a.w + b.w + c.w + d.w);
}

// ---------------------------------------------------------------- generic fp32 GEMM (kept for small shapes)
__global__ __launch_bounds__(256) void gemm_k(
    const float* __restrict__ A, int lda, int a_trans,
    const float* __restrict__ B, int ldb, int boff, int b_trans,
    const float* __restrict__ bias,
    float* __restrict__ C, int ldc, int M, int N, int K, int act) {
  __shared__ __align__(16) float As2[32][68];
  __shared__ __align__(16) float Bs2[32][68];
  const int tid = threadIdx.x;
  const int tx = tid & 15, ty = tid >> 4;
  const int m0 = blockIdx.x * 64, n0 = blockIdx.y * 64;
  float acc[4][4] = {};
  for (int k0 = 0; k0 < K; k0 += 32) {
    {
      const int r = tid >> 2, cg2 = (tid & 3) * 8;
      const float* ap = A + (long)(m0 + r) * lda + k0 + cg2;
      const float4 a0 = *(const float4*)ap;
      const float4 a1 = *(const float4*)(ap + 4);
      As2[cg2 + 0][r] = a0.x; As2[cg2 + 1][r] = a0.y; As2[cg2 + 2][r] = a0.z; As2[cg2 + 3][r] = a0.w;
      As2[cg2 + 4][r] = a1.x; As2[cg2 + 5][r] = a1.y; As2[cg2 + 6][r] = a1.z; As2[cg2 + 7][r] = a1.w;
    }
    {
      const int r = tid >> 2, cg2 = (tid & 3) * 8;
      float4 b0 = make_float4(0.f, 0.f, 0.f, 0.f);
      float4 b1 = make_float4(0.f, 0.f, 0.f, 0.f);
      if (n0 + r < N) {
        const float* bp = B + (long)(n0 + r) * ldb + boff + k0 + cg2;
        b0 = *(const float4*)bp;
        b1 = *(const float4*)(bp + 4);
      }
      Bs2[cg2 + 0][r] = b0.x; Bs2[cg2 + 1][r] = b0.y; Bs2[cg2 + 2][r] = b0.z; Bs2[cg2 + 3][r] = b0.w;
      Bs2[cg2 + 4][r] = b1.x; Bs2[cg2 + 5][r] = b1.y; Bs2[cg2 + 6][r] = b1.z; Bs2[cg2 + 7][r] = b1.w;
    }
    __syncthreads();
#pragma unroll
    for (int kk = 0; kk < 32; ++kk) {
      const float4 av = *(const float4*)&As2[kk][ty * 4];
      const float4 bv = *(const float4*)&Bs2[kk][tx * 4];
      acc[0][0] += av.x * bv.x; acc[0][1] += av.x * bv.y; acc[0][2] += av.x * bv.z; acc[0][3] += av.x * bv.w;
      acc[1][0] += av.y * bv.x; acc[1][1] += av.y * bv.y; acc[1][2] += av.y * bv.z; acc[1][3] += av.y * bv.w;
      acc[2][0] += av.z * bv.x; acc[2][1] += av.z * bv.y; acc[2][2] += av.z * bv.z; acc[2][3] += av.z * bv.w;
      acc[3][0] += av.w * bv.x; acc[3][1] += av.w * bv.y; acc[3][2] += av.w * bv.z; acc[3][3] += av.w * bv.w;
    }
    __syncthreads();
  }
#pragma unroll
  for (int i = 0; i < 4; ++i) {
    const int m = m0 + ty * 4 + i;
#pragma unroll
    for (int j = 0; j < 4; ++j) {
      const int n = n0 + tx * 4 + j;
      if (n < N) {
        float v = acc[i][j] + (bias ? bias[n] : 0.f);
        if (act == 1) v = tanhf(v);
        C[(long)m * ldc + n] = v;
      }
    }
  }
}

// ---------------------------------------------------------------- two-level grid barrier, contention-free polling
__device__ __forceinline__ void grid_barrier(unsigned* __restrict__ bar, unsigned gen) {
  __syncthreads();   // per-wave vmcnt(0) drain: all prior write-through stores are at the LLC
  const int blk = blockIdx.x, tid = threadIdx.x;
  unsigned* gctr = bar;
  unsigned* rel = bar + 1024;
  if (blk == 0) {
    if (tid == 0)
      __hip_atomic_fetch_add(gctr, 1u, __ATOMIC_RELAXED, __HIP_MEMORY_SCOPE_AGENT);
    if (tid < 16) {
      while (__hip_atomic_load(gctr + tid * 64, __ATOMIC_RELAXED, __HIP_MEMORY_SCOPE_AGENT) < gen * 16u)
        __builtin_amdgcn_s_sleep(1);
    }
    __syncthreads();
    __hip_atomic_store(rel + tid * 32, gen, __ATOMIC_RELAXED, __HIP_MEMORY_SCOPE_AGENT);
  } else {
    if (tid == 0) {
      __hip_atomic_fetch_add(gctr + (blk >> 4) * 64, 1u, __ATOMIC_RELAXED, __HIP_MEMORY_SCOPE_AGENT);
      while (__hip_atomic_load(rel + blk * 32, __ATOMIC_RELAXED, __HIP_MEMORY_SCOPE_AGENT) < gen)
        __builtin_amdgcn_s_sleep(1);
    }
  }
  __syncthreads();
}

// ---------------------------------------------------------------- fused time loop
// Rotating step-indexed state buffers (writers: write-through; readers: plain cached loads —
// each (step,address) written once before first access, so no stale line can exist).
// Patch weights live in LDS (XOR-swizzled) to keep VGPR pressure under the 256 arch cap;
// GRU weights (96 VGPR) are the only loop-persistent register block.
__global__ __launch_bounds__(256, 1) void loop_k(
    const float* __restrict__ ktil, const float* __restrict__ cbn,
    const float* __restrict__ vt, const float* __restrict__ locg,
    float* __restrict__ sbuf, float* __restrict__ rbuf,
    const float* __restrict__ w_write, const float* __restrict__ b_write,
    const float* __restrict__ w_loc, const int* __restrict__ amask,
    float* __restrict__ canvas, const float* __restrict__ gig,
    const float* __restrict__ w_ih, const float* __restrict__ w_hh,
    const float* __restrict__ b_hh, unsigned* __restrict__ bar) {
  __shared__ __align__(16) float smem[10048];   // ~40 KB phase scratch, aliased
  __shared__ __align__(16) float wpl[12288];    // 48 KB patch weights (12 rows x 1024, swizzled)
  float* sm_act = smem;          // attn/patch staging: 8*1152
  float* sm_val = smem + 9216;   // patch results: 12*16
  float* sm_sc  = smem + 9408;   // attn scores: 64
  float* sm_s   = smem;          // gru: 8*576
  float* sm_r   = smem + 4608;   // gru: 8*576
  float* sm_g   = smem + 9216;   // gru results: 16*52

  const int blk = blockIdx.x, tid = threadIdx.x, lane = tid & 63;
  const bool is_attn = (blk < 64);
  const bool is_patch = (blk >= 64) && (blk < 224);
  unsigned nsync = 0;

  // ---- patch weights -> LDS (once). col swizzle: within 32-float chunk c, float4 slot
  // j stored at slot j^(c&7) — spreads the stride-128B reads across banks (<=4-way).
  int p_rg = 0, p_bg = 0;
  if (is_patch) {
    const int g = blk - 64;
    p_bg = g & 3; p_rg = g >> 2;
    for (int idx = tid; idx < 3072; idx += 256) {     // 12 rows * 256 float4
      const int rho = idx >> 8, f4 = idx & 255;
      const int col = f4 << 2;
      const int cc = col >> 5, jj = (col >> 2) & 7;
      const int dcol = (cc << 5) | ((jj ^ (cc & 7)) << 2);
      const float* src = (rho < 10) ? (w_write + (long)(p_rg * 10 + rho) * 1024 + col)
                                    : (w_loc + (long)(rho - 10) * 1536 + col);
      *(float4*)(wpl + rho * 1024 + dcol) = *(const float4*)src;
    }
  }

  // ---- hoisted gru weights (all blocks): rows sl*3..sl*3+2 of 48  (96 persistent VGPRs)
  float4 wg[3][8];
  const int g_dg = blk & 63, g_bg = blk >> 6;
  {
    const int c = tid & 15, sl = tid >> 4;
#pragma unroll
    for (int i = 0; i < 3; ++i) {
      const int rho = sl * 3 + i;
      const float* wsrc;
      if (rho < 24) {
        const int g2 = rho >> 3, di = rho & 7;
        wsrc = w_ih + (long)(g2 * 512 + g_dg * 8 + di) * 1024 + c * 32;   // r-half cols [0,512)
      } else {
        const int rh = rho - 24, g2 = rh >> 3, di = rh & 7;
        wsrc = w_hh + (long)(g2 * 512 + g_dg * 8 + di) * 512 + c * 32;
      }
#pragma unroll
      for (int j = 0; j < 8; ++j) wg[i][j] = *(const float4*)(wsrc + 4 * j);
    }
  }
  __syncthreads();

  for (int t = 0; t <= TT; ++t) {
    const float* s_cur = sbuf + (long)t * (BB * DD);        // s_t (slot t)
    float* r_cur = rbuf + (long)t * (BB * DD);              // r_t (slot t)
    const float* r_prev = r_cur - BB * DD;                  // r_{t-1} (valid for t>=1)

    // ================= phase A =================
    if (is_attn) {
      if (t < TT) {
        const int b = blk, wrp = tid >> 6;
        const float* sb = s_cur + (long)b * DD;
        const float4 sva = *(const float4*)(sb + lane * 8);
        const float4 svb = *(const float4*)(sb + lane * 8 + 4);
        // scores: wave wrp owns rows wrp*16..+15; preload 8 rows at a time for MLP
        for (int h8 = 0; h8 < 2; ++h8) {
          const float* kbase = ktil + ((long)(b * 64 + wrp * 16 + h8 * 8)) * DD + lane * 8;
          float4 ka[8], kb2[8];
#pragma unroll
          for (int i = 0; i < 8; ++i) {
            ka[i] = *(const float4*)(kbase + (long)i * DD);
            kb2[i] = *(const float4*)(kbase + (long)i * DD + 4);
          }
#pragma unroll
          for (int i = 0; i < 8; ++i) {
            float p = dot4(ka[i], sva) + dot4(kb2[i], svb);
#pragma unroll
            for (int off = 32; off; off >>= 1) p += __shfl_xor(p, off);
            if (lane == 0) {
              const int n = wrp * 16 + h8 * 8 + i;
              float sc = p + cbn[b * 64 + n];
              if (amask[b * 64 + n] == 0) sc = -1e9f;
              sm_sc[n] = sc;
            }
          }
        }
        __syncthreads();
        if (tid < 64) {
          const float v = sm_sc[tid];
          float m = v;
#pragma unroll
          for (int off = 32; off; off >>= 1) m = fmaxf(m, __shfl_xor(m, off));
          const float e = expf(v - m);
          float l2 = e;
#pragma unroll
          for (int off = 32; off; off >>= 1) l2 += __shfl_xor(l2, off);
          sm_sc[tid] = e / l2;
        }
        __syncthreads();
        // PV: thread covers d = 2*tid, 2*tid+1; 8-deep load groups
        float rx = 0.f, ry = 0.f;
        const float* vb = vt + (long)b * 64 * DD + (tid << 1);
        for (int n0 = 0; n0 < 64; n0 += 8) {
          float2 vv[8];
#pragma unroll
          for (int i = 0; i < 8; ++i)
            vv[i] = *(const float2*)(vb + (long)(n0 + i) * DD);
#pragma unroll
          for (int i = 0; i < 8; ++i) {
            const float a = sm_sc[n0 + i];
            rx = fmaf(a, vv[i].x, rx);
            ry = fmaf(a, vv[i].y, ry);
          }
        }
        cst(r_cur + b * DD + (tid << 1), rx);
        cst(r_cur + b * DD + (tid << 1) + 1, ry);
      }
    } else if (is_patch) {
      if (t >= 1) {
        const int c = tid & 31, sl = tid >> 5;
        const int tr = sl & 3, bgsub = sl >> 2;
        for (int h = 0; h < 2; ++h) {
          __syncthreads();
          {
            const int b_i8 = tid >> 5, l = tid & 31;
            const int b = p_bg * 16 + h * 8 + b_i8;
            const float* sp = s_cur + (long)b * DD + l * 16;
            const float* rp = r_prev + (long)b * DD + l * 16;
            float* dsd = sm_act + b_i8 * 1152 + (l >> 1) * 36 + (l & 1) * 16;
            float* drd = sm_act + b_i8 * 1152 + (16 + (l >> 1)) * 36 + (l & 1) * 16;
#pragma unroll
            for (int jj = 0; jj < 4; ++jj) {
              *(float4*)(dsd + 4 * jj) = *(const float4*)(sp + 4 * jj);
              *(float4*)(drd + 4 * jj) = *(const float4*)(rp + 4 * jj);
            }
          }
          __syncthreads();
          // transient weight regs from LDS (swizzled), reused across 4 sub-batches
          float4 wreg[3][8];
#pragma unroll
          for (int i = 0; i < 3; ++i) {
            const float* wrow = wpl + (tr * 3 + i) * 1024 + (c << 5);
#pragma unroll
            for (int j = 0; j < 8; ++j)
              wreg[i][j] = *(const float4*)(wrow + ((j ^ (c & 7)) << 2));
          }
          for (int bi = 0; bi < 4; ++bi) {
            const int bl = bgsub * 4 + bi;
            const int babs = p_bg * 16 + h * 8 + bl;
            const float* ap = sm_act + bl * 1152 + c * 36;
            float a0 = 0.f, a1 = 0.f, a2 = 0.f;
#pragma unroll
            for (int j = 0; j < 8; ++j) {
              const float4 av = *(const float4*)(ap + 4 * j);
              a0 += dot4(wreg[0][j], av);
              a1 += dot4(wreg[1][j], av);
              a2 += dot4(wreg[2][j], av);
            }
#pragma unroll
            for (int m = 1; m < 32; m <<= 1) {
              a0 += __shfl_xor(a0, m);
              a1 += __shfl_xor(a1, m);
              a2 += __shfl_xor(a2, m);
            }
            if (c == 0) {
              const int bslot = h * 8 + bl;
              const float av3[3] = {a0, a1, a2};
#pragma unroll
              for (int i = 0; i < 3; ++i) {
                const int rho = tr * 3 + i;
                float v = av3[i];
                if (rho >= 10) v += locg[babs * 2 + (rho - 10)];
                sm_val[rho * 16 + bslot] = v;
              }
            }
          }
        }
        __syncthreads();
        if (tid < 160) {
          const int ri = tid >> 4, bl2 = tid & 15;
          const int row = p_rg * 10 + ri;
          const int b = p_bg * 16 + bl2;
          const float val = sm_val[ri * 16 + bl2] + b_write[row];
          const float lx = sm_val[10 * 16 + bl2];
          const float ly = sm_val[11 * 16 + bl2];
          const int jx = min(127, max(0, (int)rintf(0.5f * (tanhf(lx) + 1.f) * 127.f)));
          const int iy = min(127, max(0, (int)rintf(0.5f * (tanhf(ly) + 1.f) * 127.f)));
          const int cc = row / 25, rem = row % 25, ki = rem / 5, kj = rem % 5;
          const int y = iy + ki - 2, x = jx + kj - 2;
          if (y >= 0 && y < 128 && x >= 0 && x < 128)
            atomicAdd(canvas + ((((long)b * 16 + cc) * 128 + y) * 128 + x), val);
        }
      }
    }

    if (t == TT) break;          // last patch done; no consumer -> skip final barrier

    grid_barrier(bar, ++nsync);

    // ================= phase B: gru(t) =================
    {
      float* s_nxt = sbuf + (long)(t + 1) * (BB * DD);
      const int c = tid & 15, sl = tid >> 4;
      for (int h = 0; h < 2; ++h) {
        __syncthreads();
        {
          const int b_i8 = tid >> 5, l = tid & 31;
          const int b = g_bg * 16 + h * 8 + b_i8;
          const float* sp = s_cur + (long)b * DD + l * 16;
          const float* rp = r_cur + (long)b * DD + l * 16;
          float* dsd = sm_s + b_i8 * 576 + (l >> 1) * 36 + (l & 1) * 16;
          float* drd = sm_r + b_i8 * 576 + (l >> 1) * 36 + (l & 1) * 16;
#pragma unroll
          for (int jj = 0; jj < 4; ++jj) {
            *(float4*)(dsd + 4 * jj) = *(const float4*)(sp + 4 * jj);
            *(float4*)(drd + 4 * jj) = *(const float4*)(rp + 4 * jj);
          }
        }
        __syncthreads();
        const float* base = (sl < 8) ? sm_r : sm_s;
        for (int bl = 0; bl < 8; ++bl) {
          const float* ap = base + bl * 576 + c * 36;
          float a0 = 0.f, a1 = 0.f, a2 = 0.f;
#pragma unroll
          for (int j = 0; j < 8; ++j) {
            const float4 av = *(const float4*)(ap + 4 * j);
            a0 += dot4(wg[0][j], av);
            a1 += dot4(wg[1][j], av);
            a2 += dot4(wg[2][j], av);
          }
#pragma unroll
          for (int m = 1; m < 16; m <<= 1) {
            a0 += __shfl_xor(a0, m);
            a1 += __shfl_xor(a1, m);
            a2 += __shfl_xor(a2, m);
          }
          if (c == 0) {
            const int bslot = h * 8 + bl;
            sm_g[bslot * 52 + sl * 3 + 0] = a0;
            sm_g[bslot * 52 + sl * 3 + 1] = a1;
            sm_g[bslot * 52 + sl * 3 + 2] = a2;
          }
        }
      }
      __syncthreads();
      if (tid < 128) {
        const int b_i = tid >> 3, di = tid & 7;
        const int b = g_bg * 16 + b_i, d = g_dg * 8 + di;
        const float ir = sm_g[b_i * 52 + di]        + gig[b * 1536 + d];
        const float iz = sm_g[b_i * 52 + 8 + di]    + gig[b * 1536 + 512 + d];
        const float in = sm_g[b_i * 52 + 16 + di]   + gig[b * 1536 + 1024 + d];
        const float hr = sm_g[b_i * 52 + 24 + di]   + b_hh[d];
        const float hz = sm_g[b_i * 52 + 32 + di]   + b_hh[512 + d];
        const float hn = sm_g[b_i * 52 + 40 + di]   + b_hh[1024 + d];
        const float rg2 = 1.f / (1.f + expf(-(ir + hr)));
        const float zg = 1.f / (1.f + expf(-(iz + hz)));
        const float ng = tanhf(in + rg2 * hn);
        const float sprev = s_cur[(long)b * DD + d];
        cst(s_nxt + (long)b * DD + d, (1.f - zg) * ng + zg * sprev);
      }
    }

    grid_barrier(bar, ++nsync);
  }
}

// ---------------------------------------------------------------- launch
extern "C" void kernel_launch(void* const* d_in, const int* in_sizes, int n_in,
                              void* d_out, int out_size, void* d_ws, size_t ws_size,
                              hipStream_t stream) {
  const float* tok     = (const float*)d_in[0];
  const float* grep    = (const float*)d_in[1];
  const int*   amask   = (const int*)d_in[2];
  const float* w_init  = (const float*)d_in[3];
  const float* b_init  = (const float*)d_in[4];
  const float* wq      = (const float*)d_in[5];
  const float* bq      = (const float*)d_in[6];
  const float* wk      = (const float*)d_in[7];
  const float* bk      = (const float*)d_in[8];
  const float* wv      = (const float*)d_in[9];
  const float* bv      = (const float*)d_in[10];
  const float* w_ih    = (const float*)d_in[11];
  const float* b_ih    = (const float*)d_in[12];
  const float* w_hh    = (const float*)d_in[13];
  const float* b_hh    = (const float*)d_in[14];
  const float* w_write = (const float*)d_in[15];
  const float* b_write = (const float*)d_in[16];
  const float* w_loc   = (const float*)d_in[17];
  const float* b_loc   = (const float*)d_in[18];
  float* canvas = (float*)d_out;

  float* ws = (float*)d_ws;
  float* ktil = ws;                      // 2,097,152
  float* vtw  = ktil + 2097152;          // 2,097,152 (reused as Aqk split-K scratch first)
  float* Aqk  = vtw + 2097152;           // 262,144
  float* gig  = Aqk + 262144;            // 98,304
  float* cbn  = gig + 98304;             // 4,096
  float* sbuf = cbn + 4096;              // 33 slots * 32768 (s_0..s_32)
  float* rbuf = sbuf + 1081344;          // 32 slots * 32768 (r_0..r_31)
  float* locg = rbuf + 1048576;          // 128
  float* kqb  = locg + 128;              // 512
  float* wkbq = kqb + 512;               // 512
  float* bqbk = wkbq + 512;              // 64 (pad)
  unsigned* bar = (unsigned*)(bqbk + 64);// 16 group ctrs (stride 64) + 256 release words (stride 32)

  zero_k<<<16384, 256, 0, stream>>>(canvas, 16777216 / 4);
  vecs_k<<<4, 256, 0, stream>>>(wq, bk, wk, bq, kqb, wkbq, bqbk, bar);
  // Aqk[e,m] = sum_a wq[a,e]*wk[a,m]  — split-K(4) into vtw scratch, then combine
  gemm128_k<<<dim3(4, 8, 4), 256, 0, stream>>>(wq, 512, 1, wk, 512, 0, 1,
                                               nullptr, vtw, 262144L, 512, 0, 128, 0);
  combine4_k<<<256, 256, 0, stream>>>(vtw, Aqk);
  // ktil = tok @ Aqk^T + kqb  AND  vt = tok @ wv^T + bv  in one 512-block launch
  gemm128_dual_k<<<dim3(32, 8, 2), 256, 0, stream>>>(tok, Aqk, kqb, ktil, wv, bv, vtw);
  // cbn = tok . wkbq + bqbk
  gemm_k<<<dim3(64, 1), 256, 0, stream>>>(tok, 512, 0, wkbq, 0, 0, 0, bqbk, cbn, 1, 4096, 1, 512, 0);
  // gig = grep @ w_ih[:,512:]^T + b_ih
  gemm_k<<<dim3(1, 24), 256, 0, stream>>>(grep, 512, 0, w_ih, 1024, 512, 0, b_ih, gig, 1536, 64, 1536, 512, 0);
  // s0 = tanh(grep @ w_init^T + b_init)  -> sbuf slot 0
  gemm_k<<<dim3(1, 8), 256, 0, stream>>>(grep, 512, 0, w_init, 512, 0, 0, b_init, sbuf, 512, 64, 512, 512, 1);
  // locg = grep @ w_loc[0:2,1024:]^T + b_loc
  gemm_k<<<dim3(1, 1), 256, 0, stream>>>(grep, 512, 0, w_loc, 1536, 1024, 0, b_loc, locg, 2, 64, 2, 512, 0);

  // fused time loop: one plain kernel, rotating state buffers, two-level barrier
  loop_k<<<256, 256, 0, stream>>>(ktil, cbn, vtw, locg, sbuf, rbuf, w_write, b_write,
                                  w_loc, amask, canvas, gig, w_ih, w_hh, b_hh, bar);
}